// Round 1
// baseline (15583.820 us; speedup 1.0000x reference)
//
#include <hip/hip_runtime.h>

#define N_NODES 100000
#define N_EDGES 1600000
#define F_IN 32
#define H 128
#define H3 384
#define L_LAYERS 4
#define G_GRAPHS 64
#define NH (N_NODES * H)

__device__ __forceinline__ float sigmoidf_(float x) { return 1.0f / (1.0f + __expf(-x)); }

// ---------------- embed: x_embed = sigmoid(x @ W0^T) -> h and d_out ----------------
__global__ __launch_bounds__(256) void k_embed(const float* __restrict__ x,
                                               const float* __restrict__ W0,
                                               float* __restrict__ h,
                                               float* __restrict__ out_embed) {
    int g = blockIdx.x * 256 + threadIdx.x;  // [0, N*H)
    int n = g >> 7, jj = g & 127;
    const float4* xr = (const float4*)(x + n * F_IN);
    const float4* wr = (const float4*)(W0 + jj * F_IN);
    float acc = 0.f;
#pragma unroll
    for (int f4 = 0; f4 < F_IN / 4; ++f4) {
        float4 a = xr[f4], b = wr[f4];
        acc += a.x * b.x + a.y * b.y + a.z * b.z + a.w * b.w;
    }
    float v = sigmoidf_(acc);
    h[g] = v;
    out_embed[g] = v;
}

// ---------------- transpose 384x128 -> 128x384 (once per call) ----------------
__global__ __launch_bounds__(256) void k_transpose(const float* __restrict__ w,
                                                   float* __restrict__ wT) {
    int g = blockIdx.x * 256 + threadIdx.x;  // [0, 384*128)
    int col = g >> 7, k = g & 127;
    wT[k * H3 + col] = w[g];
}

// ---------------- conv: m = h @ W  (W = conv_w[l], [128][128] row-major) ----------------
__global__ __launch_bounds__(256) void k_conv(const float* __restrict__ h,
                                              const float* __restrict__ W,
                                              float* __restrict__ m) {
    __shared__ float hs[32][H];   // 16 KB
    __shared__ float Ws[32][H];   // 16 KB, rows = k-chunk
    const int t = threadIdx.x;
    const int nb = blockIdx.x * 32;
    {
        float4* d1 = (float4*)&hs[0][0];
        const float4* s1 = (const float4*)(h + (size_t)nb * H);
#pragma unroll
        for (int i = 0; i < 4; ++i) d1[t + 256 * i] = s1[t + 256 * i];
    }
    const int j0 = (t & 63) * 2;
    const int grp = t >> 6;  // wave-uniform
    float2 acc[8];
#pragma unroll
    for (int i = 0; i < 8; ++i) acc[i] = make_float2(0.f, 0.f);
    for (int kc = 0; kc < 4; ++kc) {
        __syncthreads();  // covers hs staging on first iter, prior reads after
        {
            float4* d1 = (float4*)&Ws[0][0];
            const float4* s1 = (const float4*)(W + kc * 32 * H);
#pragma unroll
            for (int i = 0; i < 4; ++i) d1[t + 256 * i] = s1[t + 256 * i];
        }
        __syncthreads();
#pragma unroll
        for (int kk = 0; kk < 32; ++kk) {
            int k = kc * 32 + kk;
            float2 w = *(const float2*)&Ws[kk][j0];
#pragma unroll
            for (int i = 0; i < 8; ++i) {
                float hv = hs[grp + 4 * i][k];  // broadcast (wave-uniform addr)
                acc[i].x += hv * w.x;
                acc[i].y += hv * w.y;
            }
        }
    }
#pragma unroll
    for (int i = 0; i < 8; ++i) {
        *(float2*)&m[(size_t)(nb + grp + 4 * i) * H + j0] = acc[i];
    }
}

// ---------------- edge scatter: agg[dst] += m[src] ----------------
__global__ __launch_bounds__(256) void k_edge(const int* __restrict__ ei,
                                              const float* __restrict__ m,
                                              float* __restrict__ agg) {
    int tid = blockIdx.x * 256 + threadIdx.x;  // E*32 threads
    int e = tid >> 5;
    int c = tid & 31;
    int s = ei[e];
    int d = ei[N_EDGES + e];
    float4 v = *(const float4*)&m[s * H + c * 4];
    float* ap = &agg[d * H + c * 4];
    atomicAdd(ap + 0, v.x);
    atomicAdd(ap + 1, v.y);
    atomicAdd(ap + 2, v.z);
    atomicAdd(ap + 3, v.w);
}

// ---------------- fused GRU cell: h = GRU(agg, h) ----------------
// wTI/wTH are pre-transposed [128][384] so inner reads are contiguous in col.
__global__ __launch_bounds__(256) void k_gru(const float* __restrict__ agg,
                                             float* __restrict__ h,
                                             const float* __restrict__ wTI,
                                             const float* __restrict__ wTH,
                                             const float* __restrict__ b_ih,
                                             const float* __restrict__ b_hh) {
    __shared__ float as_[32][H];   // 16 KB
    __shared__ float hs[32][H];    // 16 KB
    __shared__ float wi[8][H3];    // 12.3 KB
    __shared__ float wh[8][H3];    // 12.3 KB
    const int t = threadIdx.x;
    const int nb = blockIdx.x * 32;
    {
        float4* d1 = (float4*)&as_[0][0];
        const float4* s1 = (const float4*)(agg + (size_t)nb * H);
        float4* d2 = (float4*)&hs[0][0];
        const float4* s2 = (const float4*)(h + (size_t)nb * H);
#pragma unroll
        for (int i = 0; i < 4; ++i) {
            d1[t + 256 * i] = s1[t + 256 * i];
            d2[t + 256 * i] = s2[t + 256 * i];
        }
    }
    const int j0 = (t & 63) * 2;
    const int grp = t >> 6;  // wave-uniform
    float2 br = *(const float2*)&b_ih[j0];
    { float2 u = *(const float2*)&b_hh[j0]; br.x += u.x; br.y += u.y; }
    float2 bz = *(const float2*)&b_ih[H + j0];
    { float2 u = *(const float2*)&b_hh[H + j0]; bz.x += u.x; bz.y += u.y; }
    float2 bi = *(const float2*)&b_ih[2 * H + j0];
    float2 bh = *(const float2*)&b_hh[2 * H + j0];
    float2 rs[8], zs[8], is[8], ns[8];
#pragma unroll
    for (int i = 0; i < 8; ++i) { rs[i] = br; zs[i] = bz; is[i] = bi; ns[i] = bh; }

    for (int kc = 0; kc < 16; ++kc) {
        __syncthreads();
        {
            float4* d1 = (float4*)&wi[0][0];
            const float4* s1 = (const float4*)(wTI + kc * 8 * H3);
            float4* d2 = (float4*)&wh[0][0];
            const float4* s2 = (const float4*)(wTH + kc * 8 * H3);
#pragma unroll
            for (int i = 0; i < 3; ++i) {
                d1[t + 256 * i] = s1[t + 256 * i];
                d2[t + 256 * i] = s2[t + 256 * i];
            }
        }
        __syncthreads();
#pragma unroll
        for (int kk = 0; kk < 8; ++kk) {
            int k = kc * 8 + kk;
            float2 wri = *(const float2*)&wi[kk][j0];
            float2 wzi = *(const float2*)&wi[kk][H + j0];
            float2 wni = *(const float2*)&wi[kk][2 * H + j0];
            float2 wrh = *(const float2*)&wh[kk][j0];
            float2 wzh = *(const float2*)&wh[kk][H + j0];
            float2 wnh = *(const float2*)&wh[kk][2 * H + j0];
#pragma unroll
            for (int i = 0; i < 8; ++i) {
                int n = grp + 4 * i;
                float av = as_[n][k], hv = hs[n][k];  // broadcast
                rs[i].x += av * wri.x + hv * wrh.x;
                rs[i].y += av * wri.y + hv * wrh.y;
                zs[i].x += av * wzi.x + hv * wzh.x;
                zs[i].y += av * wzi.y + hv * wzh.y;
                is[i].x += av * wni.x;
                is[i].y += av * wni.y;
                ns[i].x += hv * wnh.x;
                ns[i].y += hv * wnh.y;
            }
        }
    }
#pragma unroll
    for (int i = 0; i < 8; ++i) {
        int n = grp + 4 * i;
        float2 hold = *(const float2*)&hs[n][j0];
        float rx = sigmoidf_(rs[i].x), ry = sigmoidf_(rs[i].y);
        float zx = sigmoidf_(zs[i].x), zy = sigmoidf_(zs[i].y);
        float nx = tanhf(is[i].x + rx * ns[i].x);
        float ny = tanhf(is[i].y + ry * ns[i].y);
        float hx = (1.f - zx) * nx + zx * hold.x;
        float hy = (1.f - zy) * ny + zy * hold.y;
        *(float2*)&h[(size_t)(nb + n) * H + j0] = make_float2(hx, hy);
    }
}

// ---------------- final linear + relu + per-graph accumulation ----------------
__global__ __launch_bounds__(256) void k_out(const float* __restrict__ h,
                                             const float* __restrict__ lw,
                                             const float* __restrict__ lb,
                                             const int* __restrict__ batch,
                                             float* __restrict__ unc,
                                             float* __restrict__ gsum,
                                             float* __restrict__ gcnt) {
    int t = threadIdx.x;
    int n = blockIdx.x * 4 + (t >> 6);
    int lane = t & 63;
    float2 hv = *(const float2*)&h[(size_t)n * H + lane * 2];
    float2 wv = *(const float2*)&lw[lane * 2];
    float v = fmaxf(hv.x, 0.f) * wv.x + fmaxf(hv.y, 0.f) * wv.y;
#pragma unroll
    for (int off = 32; off >= 1; off >>= 1) v += __shfl_xor(v, off, 64);
    if (lane == 0) {
        float o = v + lb[0];
        unc[n] = o;
        int b = batch[n];
        atomicAdd(&gsum[b], o);
        atomicAdd(&gcnt[b], 1.0f);
    }
}

__global__ __launch_bounds__(256) void k_corr(const float* __restrict__ unc,
                                              const int* __restrict__ batch,
                                              const float* __restrict__ gsum,
                                              const float* __restrict__ gcnt,
                                              float* __restrict__ corr) {
    int n = blockIdx.x * 256 + threadIdx.x;
    if (n >= N_NODES) return;
    int b = batch[n];
    float mean = gsum[b] / fmaxf(gcnt[b], 1.0f);
    corr[n] = unc[n] - mean;
}

extern "C" void kernel_launch(void* const* d_in, const int* in_sizes, int n_in,
                              void* d_out, int out_size, void* d_ws, size_t ws_size,
                              hipStream_t stream) {
    const float* x      = (const float*)d_in[0];
    const int*   ei     = (const int*)d_in[1];
    const int*   batch  = (const int*)d_in[2];
    // d_in[3] = num_graphs (64, hard-coded)
    const float* W0     = (const float*)d_in[4];
    const float* conv_w = (const float*)d_in[5];
    const float* w_ih   = (const float*)d_in[6];
    const float* b_ih   = (const float*)d_in[7];
    const float* w_hh   = (const float*)d_in[8];
    const float* b_hh   = (const float*)d_in[9];
    const float* lin1_w = (const float*)d_in[10];
    const float* lin1_b = (const float*)d_in[11];

    float* out = (float*)d_out;
    float* ws  = (float*)d_ws;

    float* h    = ws;                       // N*H
    float* m    = ws + (size_t)NH;          // N*H
    float* agg  = ws + 2 * (size_t)NH;      // N*H
    float* wTI  = ws + 3 * (size_t)NH;      // 128*384
    float* wTH  = wTI + (size_t)H * H3;     // 128*384
    float* gsum = wTH + (size_t)H * H3;     // G
    float* gcnt = gsum + G_GRAPHS;          // G

    float* out_corr  = out;                         // [N]
    float* out_embed = out + N_NODES;               // [N*H]
    float* out_unc   = out + N_NODES + (size_t)NH;  // [N]

    hipMemsetAsync(gsum, 0, 2 * G_GRAPHS * sizeof(float), stream);
    k_transpose<<<192, 256, 0, stream>>>(w_ih, wTI);
    k_transpose<<<192, 256, 0, stream>>>(w_hh, wTH);
    k_embed<<<NH / 256, 256, 0, stream>>>(x, W0, h, out_embed);

    for (int l = 0; l < L_LAYERS; ++l) {
        k_conv<<<N_NODES / 32, 256, 0, stream>>>(h, conv_w + (size_t)l * H * H, m);
        hipMemsetAsync(agg, 0, (size_t)NH * sizeof(float), stream);
        k_edge<<<(N_EDGES / 8), 256, 0, stream>>>(ei, m, agg);  // E*32/256
        k_gru<<<N_NODES / 32, 256, 0, stream>>>(agg, h, wTI, wTH, b_ih, b_hh);
    }

    k_out<<<N_NODES / 4, 256, 0, stream>>>(h, lin1_w, lin1_b, batch, out_unc, gsum, gcnt);
    k_corr<<<(N_NODES + 255) / 256, 256, 0, stream>>>(out_unc, batch, gsum, gcnt, out_corr);
}

// Round 2
// 5176.178 us; speedup vs baseline: 3.0107x; 3.0107x over previous
//
#include <hip/hip_runtime.h>

#define N_NODES 100000
#define N_EDGES 1600000
#define F_IN 32
#define H 128
#define H3 384
#define L_LAYERS 4
#define G_GRAPHS 64
#define NH (N_NODES * H)
#define SCAN_BS 1024
#define NBLK ((N_NODES + SCAN_BS - 1) / SCAN_BS)

__device__ __forceinline__ float sigmoidf_(float x) { return 1.0f / (1.0f + __expf(-x)); }

// ---------------- embed: x_embed = sigmoid(x @ W0^T) -> h and d_out ----------------
__global__ __launch_bounds__(256) void k_embed(const float* __restrict__ x,
                                               const float* __restrict__ W0,
                                               float* __restrict__ h,
                                               float* __restrict__ out_embed) {
    int g = blockIdx.x * 256 + threadIdx.x;  // [0, N*H)
    int n = g >> 7, jj = g & 127;
    const float4* xr = (const float4*)(x + n * F_IN);
    const float4* wr = (const float4*)(W0 + jj * F_IN);
    float acc = 0.f;
#pragma unroll
    for (int f4 = 0; f4 < F_IN / 4; ++f4) {
        float4 a = xr[f4], b = wr[f4];
        acc += a.x * b.x + a.y * b.y + a.z * b.z + a.w * b.w;
    }
    float v = sigmoidf_(acc);
    h[g] = v;
    out_embed[g] = v;
}

// ---------------- transpose 384x128 -> 128x384 (once per call) ----------------
__global__ __launch_bounds__(256) void k_transpose(const float* __restrict__ w,
                                                   float* __restrict__ wT) {
    int g = blockIdx.x * 256 + threadIdx.x;  // [0, 384*128)
    int col = g >> 7, k = g & 127;
    wT[k * H3 + col] = w[g];
}

// ---------------- CSR build: histogram of dst ----------------
__global__ __launch_bounds__(256) void k_hist(const int* __restrict__ ei,
                                              int* __restrict__ deg) {
    int e = blockIdx.x * 256 + threadIdx.x;
    if (e >= N_EDGES) return;
    atomicAdd(&deg[ei[N_EDGES + e]], 1);
}

// per-block (1024-elem) sums
__global__ __launch_bounds__(256) void k_blocksum(const int* __restrict__ deg,
                                                  int* __restrict__ bsum) {
    int b = blockIdx.x, t = threadIdx.x;
    int base = b * SCAN_BS + t * 4;
    int s = 0;
#pragma unroll
    for (int i = 0; i < 4; ++i) {
        int idx = base + i;
        if (idx < N_NODES) s += deg[idx];
    }
#pragma unroll
    for (int off = 1; off < 64; off <<= 1) s += __shfl_xor(s, off, 64);
    __shared__ int wtot[4];
    if ((t & 63) == 0) wtot[t >> 6] = s;
    __syncthreads();
    if (t == 0) bsum[b] = wtot[0] + wtot[1] + wtot[2] + wtot[3];
}

// exclusive scan of the 98 block sums (single thread — 98 elems, once per call)
__global__ void k_topscan(const int* __restrict__ bsum, int* __restrict__ boff) {
    if (threadIdx.x == 0 && blockIdx.x == 0) {
        int acc = 0;
        for (int i = 0; i < NBLK; ++i) { boff[i] = acc; acc += bsum[i]; }
    }
}

// block-local exclusive scan + global offset -> offs, cursor
__global__ __launch_bounds__(256) void k_scanwrite(const int* __restrict__ deg,
                                                   const int* __restrict__ boff,
                                                   int* __restrict__ offs,
                                                   int* __restrict__ cursor) {
    int b = blockIdx.x, t = threadIdx.x;
    int base = b * SCAN_BS + t * 4;
    int v[4];
    int s = 0;
#pragma unroll
    for (int i = 0; i < 4; ++i) {
        int idx = base + i;
        v[i] = (idx < N_NODES) ? deg[idx] : 0;
        s += v[i];
    }
    int lane = t & 63, w = t >> 6;
    int inc = s;
#pragma unroll
    for (int off = 1; off < 64; off <<= 1) {
        int u = __shfl_up(inc, off, 64);
        if (lane >= off) inc += u;
    }
    __shared__ int wtot[4];
    if (lane == 63) wtot[w] = inc;
    __syncthreads();
    int wpre = 0;
#pragma unroll
    for (int i = 0; i < 4; ++i)
        if (i < w) wpre += wtot[i];
    int run = inc - s + wpre + boff[b];
#pragma unroll
    for (int i = 0; i < 4; ++i) {
        int idx = base + i;
        if (idx < N_NODES) { offs[idx] = run; cursor[idx] = run; run += v[i]; }
    }
    if (b == 0 && t == 0) offs[N_NODES] = N_EDGES;
}

// scatter src ids into CSR buckets
__global__ __launch_bounds__(256) void k_scatter(const int* __restrict__ ei,
                                                 int* __restrict__ cursor,
                                                 int* __restrict__ csr) {
    int e = blockIdx.x * 256 + threadIdx.x;
    if (e >= N_EDGES) return;
    int d = ei[N_EDGES + e];
    int pos = atomicAdd(&cursor[d], 1);
    csr[pos] = ei[e];
}

// ---------------- conv: m = h @ W  (W = conv_w[l], [128][128] row-major) ----------------
__global__ __launch_bounds__(256) void k_conv(const float* __restrict__ h,
                                              const float* __restrict__ W,
                                              float* __restrict__ m) {
    __shared__ float hs[32][H];   // 16 KB
    __shared__ float Ws[32][H];   // 16 KB, rows = k-chunk
    const int t = threadIdx.x;
    const int nb = blockIdx.x * 32;
    {
        float4* d1 = (float4*)&hs[0][0];
        const float4* s1 = (const float4*)(h + (size_t)nb * H);
#pragma unroll
        for (int i = 0; i < 4; ++i) d1[t + 256 * i] = s1[t + 256 * i];
    }
    const int j0 = (t & 63) * 2;
    const int grp = t >> 6;  // wave-uniform
    float2 acc[8];
#pragma unroll
    for (int i = 0; i < 8; ++i) acc[i] = make_float2(0.f, 0.f);
    for (int kc = 0; kc < 4; ++kc) {
        __syncthreads();
        {
            float4* d1 = (float4*)&Ws[0][0];
            const float4* s1 = (const float4*)(W + kc * 32 * H);
#pragma unroll
            for (int i = 0; i < 4; ++i) d1[t + 256 * i] = s1[t + 256 * i];
        }
        __syncthreads();
#pragma unroll
        for (int kk = 0; kk < 32; ++kk) {
            int k = kc * 32 + kk;
            float2 w = *(const float2*)&Ws[kk][j0];
#pragma unroll
            for (int i = 0; i < 8; ++i) {
                float hv = hs[grp + 4 * i][k];  // broadcast (wave-uniform addr)
                acc[i].x += hv * w.x;
                acc[i].y += hv * w.y;
            }
        }
    }
#pragma unroll
    for (int i = 0; i < 8; ++i) {
        *(float2*)&m[(size_t)(nb + grp + 4 * i) * H + j0] = acc[i];
    }
}

// ---------------- aggregate: agg[n] = sum over in-edges of m[src] (no atomics) ----------
__global__ __launch_bounds__(256) void k_agg(const int* __restrict__ offs,
                                             const int* __restrict__ csr,
                                             const float* __restrict__ m,
                                             float* __restrict__ agg) {
    int t = threadIdx.x;
    int n = blockIdx.x * 4 + (t >> 6);
    int lane = t & 63;
    int beg = offs[n], end = offs[n + 1];
    float2 acc = make_float2(0.f, 0.f);
    int i = beg;
    for (; i + 1 < end; i += 2) {
        int s0 = csr[i], s1 = csr[i + 1];
        float2 a = *(const float2*)&m[(size_t)s0 * H + lane * 2];
        float2 b = *(const float2*)&m[(size_t)s1 * H + lane * 2];
        acc.x += a.x + b.x;
        acc.y += a.y + b.y;
    }
    if (i < end) {
        int s0 = csr[i];
        float2 a = *(const float2*)&m[(size_t)s0 * H + lane * 2];
        acc.x += a.x;
        acc.y += a.y;
    }
    *(float2*)&agg[(size_t)n * H + lane * 2] = acc;
}

// ---------------- fused GRU cell: h = GRU(agg, h) ----------------
__global__ __launch_bounds__(256) void k_gru(const float* __restrict__ agg,
                                             float* __restrict__ h,
                                             const float* __restrict__ wTI,
                                             const float* __restrict__ wTH,
                                             const float* __restrict__ b_ih,
                                             const float* __restrict__ b_hh) {
    __shared__ float as_[32][H];   // 16 KB
    __shared__ float hs[32][H];    // 16 KB
    __shared__ float wi[8][H3];    // 12.3 KB
    __shared__ float wh[8][H3];    // 12.3 KB
    const int t = threadIdx.x;
    const int nb = blockIdx.x * 32;
    {
        float4* d1 = (float4*)&as_[0][0];
        const float4* s1 = (const float4*)(agg + (size_t)nb * H);
        float4* d2 = (float4*)&hs[0][0];
        const float4* s2 = (const float4*)(h + (size_t)nb * H);
#pragma unroll
        for (int i = 0; i < 4; ++i) {
            d1[t + 256 * i] = s1[t + 256 * i];
            d2[t + 256 * i] = s2[t + 256 * i];
        }
    }
    const int j0 = (t & 63) * 2;
    const int grp = t >> 6;  // wave-uniform
    float2 br = *(const float2*)&b_ih[j0];
    { float2 u = *(const float2*)&b_hh[j0]; br.x += u.x; br.y += u.y; }
    float2 bz = *(const float2*)&b_ih[H + j0];
    { float2 u = *(const float2*)&b_hh[H + j0]; bz.x += u.x; bz.y += u.y; }
    float2 bi = *(const float2*)&b_ih[2 * H + j0];
    float2 bh = *(const float2*)&b_hh[2 * H + j0];
    float2 rs[8], zs[8], is[8], ns[8];
#pragma unroll
    for (int i = 0; i < 8; ++i) { rs[i] = br; zs[i] = bz; is[i] = bi; ns[i] = bh; }

    for (int kc = 0; kc < 16; ++kc) {
        __syncthreads();
        {
            float4* d1 = (float4*)&wi[0][0];
            const float4* s1 = (const float4*)(wTI + kc * 8 * H3);
            float4* d2 = (float4*)&wh[0][0];
            const float4* s2 = (const float4*)(wTH + kc * 8 * H3);
#pragma unroll
            for (int i = 0; i < 3; ++i) {
                d1[t + 256 * i] = s1[t + 256 * i];
                d2[t + 256 * i] = s2[t + 256 * i];
            }
        }
        __syncthreads();
#pragma unroll
        for (int kk = 0; kk < 8; ++kk) {
            int k = kc * 8 + kk;
            float2 wri = *(const float2*)&wi[kk][j0];
            float2 wzi = *(const float2*)&wi[kk][H + j0];
            float2 wni = *(const float2*)&wi[kk][2 * H + j0];
            float2 wrh = *(const float2*)&wh[kk][j0];
            float2 wzh = *(const float2*)&wh[kk][H + j0];
            float2 wnh = *(const float2*)&wh[kk][2 * H + j0];
#pragma unroll
            for (int i = 0; i < 8; ++i) {
                int n = grp + 4 * i;
                float av = as_[n][k], hv = hs[n][k];  // broadcast
                rs[i].x += av * wri.x + hv * wrh.x;
                rs[i].y += av * wri.y + hv * wrh.y;
                zs[i].x += av * wzi.x + hv * wzh.x;
                zs[i].y += av * wzi.y + hv * wzh.y;
                is[i].x += av * wni.x;
                is[i].y += av * wni.y;
                ns[i].x += hv * wnh.x;
                ns[i].y += hv * wnh.y;
            }
        }
    }
#pragma unroll
    for (int i = 0; i < 8; ++i) {
        int n = grp + 4 * i;
        float2 hold = *(const float2*)&hs[n][j0];
        float rx = sigmoidf_(rs[i].x), ry = sigmoidf_(rs[i].y);
        float zx = sigmoidf_(zs[i].x), zy = sigmoidf_(zs[i].y);
        float nx = tanhf(is[i].x + rx * ns[i].x);
        float ny = tanhf(is[i].y + ry * ns[i].y);
        float hx = (1.f - zx) * nx + zx * hold.x;
        float hy = (1.f - zy) * ny + zy * hold.y;
        *(float2*)&h[(size_t)(nb + n) * H + j0] = make_float2(hx, hy);
    }
}

// ---------------- final linear + relu + per-graph accumulation ----------------
__global__ __launch_bounds__(256) void k_out(const float* __restrict__ h,
                                             const float* __restrict__ lw,
                                             const float* __restrict__ lb,
                                             const int* __restrict__ batch,
                                             float* __restrict__ unc,
                                             float* __restrict__ gsum,
                                             float* __restrict__ gcnt) {
    int t = threadIdx.x;
    int n = blockIdx.x * 4 + (t >> 6);
    int lane = t & 63;
    float2 hv = *(const float2*)&h[(size_t)n * H + lane * 2];
    float2 wv = *(const float2*)&lw[lane * 2];
    float v = fmaxf(hv.x, 0.f) * wv.x + fmaxf(hv.y, 0.f) * wv.y;
#pragma unroll
    for (int off = 32; off >= 1; off >>= 1) v += __shfl_xor(v, off, 64);
    if (lane == 0) {
        float o = v + lb[0];
        unc[n] = o;
        int b = batch[n];
        atomicAdd(&gsum[b], o);
        atomicAdd(&gcnt[b], 1.0f);
    }
}

__global__ __launch_bounds__(256) void k_corr(const float* __restrict__ unc,
                                              const int* __restrict__ batch,
                                              const float* __restrict__ gsum,
                                              const float* __restrict__ gcnt,
                                              float* __restrict__ corr) {
    int n = blockIdx.x * 256 + threadIdx.x;
    if (n >= N_NODES) return;
    int b = batch[n];
    float mean = gsum[b] / fmaxf(gcnt[b], 1.0f);
    corr[n] = unc[n] - mean;
}

extern "C" void kernel_launch(void* const* d_in, const int* in_sizes, int n_in,
                              void* d_out, int out_size, void* d_ws, size_t ws_size,
                              hipStream_t stream) {
    const float* x      = (const float*)d_in[0];
    const int*   ei     = (const int*)d_in[1];
    const int*   batch  = (const int*)d_in[2];
    const float* W0     = (const float*)d_in[4];
    const float* conv_w = (const float*)d_in[5];
    const float* w_ih   = (const float*)d_in[6];
    const float* b_ih   = (const float*)d_in[7];
    const float* w_hh   = (const float*)d_in[8];
    const float* b_hh   = (const float*)d_in[9];
    const float* lin1_w = (const float*)d_in[10];
    const float* lin1_b = (const float*)d_in[11];

    float* out = (float*)d_out;
    float* ws  = (float*)d_ws;

    float* h    = ws;                       // N*H
    float* m    = ws + (size_t)NH;          // N*H
    float* agg  = ws + 2 * (size_t)NH;      // N*H
    float* wTI  = ws + 3 * (size_t)NH;      // 128*384
    float* wTH  = wTI + (size_t)H * H3;     // 128*384
    float* gsum = wTH + (size_t)H * H3;     // G
    float* gcnt = gsum + G_GRAPHS;          // G
    int*   deg    = (int*)(gcnt + G_GRAPHS);        // N
    int*   offs   = deg + N_NODES;                  // N+1
    int*   cursor = offs + N_NODES + 1;             // N
    int*   bsum   = cursor + N_NODES;               // NBLK
    int*   boff   = bsum + NBLK;                    // NBLK
    int*   csr    = boff + NBLK;                    // E

    float* out_corr  = out;                         // [N]
    float* out_embed = out + N_NODES;               // [N*H]
    float* out_unc   = out + N_NODES + (size_t)NH;  // [N]

    hipMemsetAsync(gsum, 0, 2 * G_GRAPHS * sizeof(float), stream);
    hipMemsetAsync(deg, 0, N_NODES * sizeof(int), stream);

    k_transpose<<<192, 256, 0, stream>>>(w_ih, wTI);
    k_transpose<<<192, 256, 0, stream>>>(w_hh, wTH);
    k_embed<<<NH / 256, 256, 0, stream>>>(x, W0, h, out_embed);

    // CSR build (edge_index is constant across layers)
    k_hist<<<(N_EDGES + 255) / 256, 256, 0, stream>>>(ei, deg);
    k_blocksum<<<NBLK, 256, 0, stream>>>(deg, bsum);
    k_topscan<<<1, 64, 0, stream>>>(bsum, boff);
    k_scanwrite<<<NBLK, 256, 0, stream>>>(deg, boff, offs, cursor);
    k_scatter<<<(N_EDGES + 255) / 256, 256, 0, stream>>>(ei, cursor, csr);

    for (int l = 0; l < L_LAYERS; ++l) {
        k_conv<<<N_NODES / 32, 256, 0, stream>>>(h, conv_w + (size_t)l * H * H, m);
        k_agg<<<N_NODES / 4, 256, 0, stream>>>(offs, csr, m, agg);
        k_gru<<<N_NODES / 32, 256, 0, stream>>>(agg, h, wTI, wTH, b_ih, b_hh);
    }

    k_out<<<N_NODES / 4, 256, 0, stream>>>(h, lin1_w, lin1_b, batch, out_unc, gsum, gcnt);
    k_corr<<<(N_NODES + 255) / 256, 256, 0, stream>>>(out_unc, batch, gsum, gcnt, out_corr);
}

// Round 4
// 2531.422 us; speedup vs baseline: 6.1562x; 2.0448x over previous
//
#include <hip/hip_runtime.h>

#define N_NODES 100000
#define N_EDGES 1600000
#define F_IN 32
#define H 128
#define H3 384
#define L_LAYERS 4
#define G_GRAPHS 64
#define NH (N_NODES * H)
#define SCAN_BS 1024
#define NBLK ((N_NODES + SCAN_BS - 1) / SCAN_BS)

typedef short bfrag __attribute__((ext_vector_type(8)));   // 8 bf16 = 4 VGPR
typedef float facc __attribute__((ext_vector_type(4)));    // 4 fp32 acc
typedef unsigned short u16x8 __attribute__((ext_vector_type(8)));

__device__ __forceinline__ float sigmoidf_(float x) { return 1.0f / (1.0f + __expf(-x)); }
__device__ __forceinline__ float bf2f(unsigned int u) { return __uint_as_float(u << 16); }
__device__ __forceinline__ unsigned short f2bf(float f) {
    unsigned int b = __float_as_uint(f);
    return (unsigned short)((b + 0x7FFF + ((b >> 16) & 1)) >> 16);
}
__device__ __forceinline__ facc mfma16(bfrag a, bfrag b, facc c) {
    return __builtin_amdgcn_mfma_f32_16x16x32_bf16(a, b, c, 0, 0, 0);
}

// ---------------- embed: x_embed = sigmoid(x @ W0^T) -> split h + fp32 out ----------------
__global__ __launch_bounds__(256) void k_embed(const float* __restrict__ x,
                                               const float* __restrict__ W0,
                                               unsigned short* __restrict__ hH,
                                               unsigned short* __restrict__ hL,
                                               float* __restrict__ out_embed) {
    int g = blockIdx.x * 256 + threadIdx.x;  // [0, N*H)
    int n = g >> 7, jj = g & 127;
    const float4* xr = (const float4*)(x + n * F_IN);
    const float4* wr = (const float4*)(W0 + jj * F_IN);
    float acc = 0.f;
#pragma unroll
    for (int f4 = 0; f4 < F_IN / 4; ++f4) {
        float4 a = xr[f4], b = wr[f4];
        acc += a.x * b.x + a.y * b.y + a.z * b.z + a.w * b.w;
    }
    float v = sigmoidf_(acc);
    out_embed[g] = v;
    unsigned short hi = f2bf(v);
    hH[g] = hi;
    hL[g] = f2bf(v - bf2f(hi));
}

// ---------------- CSR build ----------------
__global__ __launch_bounds__(256) void k_hist(const int* __restrict__ ei, int* __restrict__ deg) {
    int e = blockIdx.x * 256 + threadIdx.x;
    if (e >= N_EDGES) return;
    atomicAdd(&deg[ei[N_EDGES + e]], 1);
}

__global__ __launch_bounds__(256) void k_blocksum(const int* __restrict__ deg, int* __restrict__ bsum) {
    int b = blockIdx.x, t = threadIdx.x;
    int base = b * SCAN_BS + t * 4;
    int s = 0;
#pragma unroll
    for (int i = 0; i < 4; ++i) {
        int idx = base + i;
        if (idx < N_NODES) s += deg[idx];
    }
#pragma unroll
    for (int off = 1; off < 64; off <<= 1) s += __shfl_xor(s, off, 64);
    __shared__ int wtot[4];
    if ((t & 63) == 0) wtot[t >> 6] = s;
    __syncthreads();
    if (t == 0) bsum[b] = wtot[0] + wtot[1] + wtot[2] + wtot[3];
}

__global__ void k_topscan(const int* __restrict__ bsum, int* __restrict__ boff) {
    if (threadIdx.x == 0 && blockIdx.x == 0) {
        int acc = 0;
        for (int i = 0; i < NBLK; ++i) { boff[i] = acc; acc += bsum[i]; }
    }
}

__global__ __launch_bounds__(256) void k_scanwrite(const int* __restrict__ deg,
                                                   const int* __restrict__ boff,
                                                   int* __restrict__ offs,
                                                   int* __restrict__ cursor) {
    int b = blockIdx.x, t = threadIdx.x;
    int base = b * SCAN_BS + t * 4;
    int v[4];
    int s = 0;
#pragma unroll
    for (int i = 0; i < 4; ++i) {
        int idx = base + i;
        v[i] = (idx < N_NODES) ? deg[idx] : 0;
        s += v[i];
    }
    int lane = t & 63, w = t >> 6;
    int inc = s;
#pragma unroll
    for (int off = 1; off < 64; off <<= 1) {
        int u = __shfl_up(inc, off, 64);
        if (lane >= off) inc += u;
    }
    __shared__ int wtot[4];
    if (lane == 63) wtot[w] = inc;
    __syncthreads();
    int wpre = 0;
#pragma unroll
    for (int i = 0; i < 4; ++i)
        if (i < w) wpre += wtot[i];
    int run = inc - s + wpre + boff[b];
#pragma unroll
    for (int i = 0; i < 4; ++i) {
        int idx = base + i;
        if (idx < N_NODES) { offs[idx] = run; cursor[idx] = run; run += v[i]; }
    }
    if (b == 0 && t == 0) offs[N_NODES] = N_EDGES;
}

__global__ __launch_bounds__(256) void k_scatter(const int* __restrict__ ei,
                                                 int* __restrict__ cursor,
                                                 int* __restrict__ csr) {
    int e = blockIdx.x * 256 + threadIdx.x;
    if (e >= N_EDGES) return;
    int d = ei[N_EDGES + e];
    int pos = atomicAdd(&cursor[d], 1);
    csr[pos] = ei[e];
}

// ---------------- prep: build gate weights W2[256][512] in fragment-major split bf16 ------
// cols: 0-127 r | 128-255 z | 256-383 i_n (k<128 only) | 384-511 h_n (k>=128 only)
// layout: flat[((kc*32 + ntg)*64 + lane)*8 + j]; k = kc*32 + (lane>>4)*8 + j; c = ntg*16 + (lane&15)
__global__ __launch_bounds__(256) void k_prepw(const float* __restrict__ w_ih,
                                               const float* __restrict__ w_hh,
                                               unsigned short* __restrict__ WfH,
                                               unsigned short* __restrict__ WfL) {
    int tid = blockIdx.x * 256 + threadIdx.x;  // [0, 16384)
    int kc = tid >> 11;
    int ntg = (tid >> 6) & 31;
    int l = tid & 63;
    int c = ntg * 16 + (l & 15);
    int g = c >> 7;
    int jg = c & 127;
#pragma unroll
    for (int j = 0; j < 8; ++j) {
        int k = kc * 32 + ((l >> 4) << 3) + j;
        float val;
        if (k < 128) {
            val = (g < 3) ? w_ih[(g * 128 + jg) * 128 + k] : 0.f;
        } else {
            int k2 = k - 128;
            if (g == 2) val = 0.f;
            else val = w_hh[((g == 3 ? 256 : g * 128) + jg) * 128 + k2];
        }
        unsigned short hi = f2bf(val);
        WfH[tid * 8 + j] = hi;
        WfL[tid * 8 + j] = f2bf(val - bf2f(hi));
    }
}

// ---------------- conv: m = h @ W (h reconstructed from split) ----------------
__global__ __launch_bounds__(256) void k_conv(const unsigned short* __restrict__ hH,
                                              const unsigned short* __restrict__ hL,
                                              const float* __restrict__ W,
                                              float* __restrict__ m) {
    __shared__ float hs[32][H];   // 16 KB
    __shared__ float Ws[32][H];   // 16 KB
    const int t = threadIdx.x;
    const int nb = blockIdx.x * 32;
    {
        const u16x8* sh = (const u16x8*)(hH + (size_t)nb * H);
        const u16x8* sl = (const u16x8*)(hL + (size_t)nb * H);
        float* fl = &hs[0][0];
#pragma unroll
        for (int i = 0; i < 2; ++i) {
            int idx = t + 256 * i;
            u16x8 vh = sh[idx], vl = sl[idx];
            float4 f0, f1;
            f0.x = bf2f(vh[0]) + bf2f(vl[0]);
            f0.y = bf2f(vh[1]) + bf2f(vl[1]);
            f0.z = bf2f(vh[2]) + bf2f(vl[2]);
            f0.w = bf2f(vh[3]) + bf2f(vl[3]);
            f1.x = bf2f(vh[4]) + bf2f(vl[4]);
            f1.y = bf2f(vh[5]) + bf2f(vl[5]);
            f1.z = bf2f(vh[6]) + bf2f(vl[6]);
            f1.w = bf2f(vh[7]) + bf2f(vl[7]);
            *(float4*)&fl[idx * 8] = f0;
            *(float4*)&fl[idx * 8 + 4] = f1;
        }
    }
    const int j0 = (t & 63) * 2;
    const int grp = t >> 6;
    float2 acc[8];
#pragma unroll
    for (int i = 0; i < 8; ++i) acc[i] = make_float2(0.f, 0.f);
    for (int kc = 0; kc < 4; ++kc) {
        __syncthreads();
        {
            float4* d1 = (float4*)&Ws[0][0];
            const float4* s1 = (const float4*)(W + kc * 32 * H);
#pragma unroll
            for (int i = 0; i < 4; ++i) d1[t + 256 * i] = s1[t + 256 * i];
        }
        __syncthreads();
#pragma unroll
        for (int kk = 0; kk < 32; ++kk) {
            int k = kc * 32 + kk;
            float2 w = *(const float2*)&Ws[kk][j0];
#pragma unroll
            for (int i = 0; i < 8; ++i) {
                float hv = hs[grp + 4 * i][k];
                acc[i].x += hv * w.x;
                acc[i].y += hv * w.y;
            }
        }
    }
#pragma unroll
    for (int i = 0; i < 8; ++i) {
        *(float2*)&m[(size_t)(nb + grp + 4 * i) * H + j0] = acc[i];
    }
}

// ---------------- aggregate: agg[n] = sum_{in-edges} m[src]; emit split bf16 ----------
__global__ __launch_bounds__(256) void k_agg(const int* __restrict__ offs,
                                             const int* __restrict__ csr,
                                             const float* __restrict__ m,
                                             unsigned short* __restrict__ aggH,
                                             unsigned short* __restrict__ aggL) {
    int t = threadIdx.x;
    int n = blockIdx.x * 4 + (t >> 6);
    int lane = t & 63;
    int beg = offs[n], end = offs[n + 1];
    float2 acc = make_float2(0.f, 0.f);
    int i = beg;
    for (; i + 1 < end; i += 2) {
        int s0 = csr[i], s1 = csr[i + 1];
        float2 a = *(const float2*)&m[(size_t)s0 * H + lane * 2];
        float2 b = *(const float2*)&m[(size_t)s1 * H + lane * 2];
        acc.x += a.x + b.x;
        acc.y += a.y + b.y;
    }
    if (i < end) {
        float2 a = *(const float2*)&m[(size_t)csr[i] * H + lane * 2];
        acc.x += a.x;
        acc.y += a.y;
    }
    unsigned short hx = f2bf(acc.x);
    unsigned short lx = f2bf(acc.x - bf2f(hx));
    unsigned short hy = f2bf(acc.y);
    unsigned short ly = f2bf(acc.y - bf2f(hy));
    *(unsigned int*)&aggH[(size_t)n * H + lane * 2] = (unsigned int)hx | ((unsigned int)hy << 16);
    *(unsigned int*)&aggL[(size_t)n * H + lane * 2] = (unsigned int)lx | ((unsigned int)ly << 16);
}

// ---------------- fused MFMA gates GEMM + GRU epilogue ----------------
// block: 32 rows x 512 cols; 4 waves, each 32r x 128c (2 mtiles x 8 ntiles)
__global__ __launch_bounds__(256, 2) void k_ggru(const unsigned short* __restrict__ aggH,
                                                 const unsigned short* __restrict__ aggL,
                                                 unsigned short* __restrict__ hH,
                                                 unsigned short* __restrict__ hL,
                                                 const unsigned short* __restrict__ WfH,
                                                 const unsigned short* __restrict__ WfL,
                                                 const float* __restrict__ b_ih,
                                                 const float* __restrict__ b_hh) {
    __shared__ short Ast[2][2][64][8];   // [hi/lo][mtile][lane][8] = 4 KB
    __shared__ float gates[32][516];     // 64.5 KB (pad 516 kills epilogue bank conflicts)
    const int t = threadIdx.x;
    const int wv = t >> 6, l = t & 63;
    const int nb = blockIdx.x * 32;

    facc acc[2][8];
#pragma unroll
    for (int mt = 0; mt < 2; ++mt)
#pragma unroll
        for (int nt = 0; nt < 8; ++nt) acc[mt][nt] = (facc)(0.f);

    // staging role: wave wv stages (part = wv>>1 [hi/lo], mt_s = wv&1)
    const int part = wv >> 1, mt_s = wv & 1;
    const int srow = nb + mt_s * 16 + (l & 15);
    const int kb8 = (l >> 4) << 3;
    const unsigned short* aggP = part ? aggL : aggH;
    const unsigned short* hP = part ? hL : hH;

    // B fragment base (fragment-major prepped)
    const short* pBH = (const short*)WfH + (wv * 512 + l) * 8;
    const short* pBL = (const short*)WfL + (wv * 512 + l) * 8;

    bfrag sA = *(const bfrag*)(aggP + (size_t)srow * H + kb8);  // kc=0
    for (int kc = 0; kc < 8; ++kc) {
        __syncthreads();  // prior reads of Ast done
        *(bfrag*)&Ast[part][mt_s][l][0] = sA;
        if (kc < 7) {
            int kn = kc + 1;
            const unsigned short* base = (kn < 4) ? aggP : hP;
            sA = *(const bfrag*)(base + (size_t)srow * H + ((kn & 3) << 5) + kb8);
        }
        __syncthreads();
        bfrag a0h = *(const bfrag*)&Ast[0][0][l][0];
        bfrag a1h = *(const bfrag*)&Ast[0][1][l][0];
        bfrag a0l = *(const bfrag*)&Ast[1][0][l][0];
        bfrag a1l = *(const bfrag*)&Ast[1][1][l][0];
        const short* bh = pBH + kc * 16384;
        const short* bl = pBL + kc * 16384;
#pragma unroll
        for (int nt = 0; nt < 8; ++nt) {
            bfrag wH = *(const bfrag*)(bh + nt * 512);
            bfrag wL = *(const bfrag*)(bl + nt * 512);
            acc[0][nt] = mfma16(a0h, wH, acc[0][nt]);
            acc[0][nt] = mfma16(a0h, wL, acc[0][nt]);
            acc[0][nt] = mfma16(a0l, wH, acc[0][nt]);
            acc[1][nt] = mfma16(a1h, wH, acc[1][nt]);
            acc[1][nt] = mfma16(a1h, wL, acc[1][nt]);
            acc[1][nt] = mfma16(a1l, wH, acc[1][nt]);
        }
    }

    // acc -> gates LDS.  C/D layout: col = lane&15, row = (lane>>4)*4 + reg
#pragma unroll
    for (int mt = 0; mt < 2; ++mt)
#pragma unroll
        for (int nt = 0; nt < 8; ++nt) {
            int r0 = mt * 16 + ((l >> 4) << 2);
            int c = wv * 128 + nt * 16 + (l & 15);
#pragma unroll
            for (int reg = 0; reg < 4; ++reg) gates[r0 + reg][c] = acc[mt][nt][reg];
        }
    __syncthreads();

    // GRU epilogue: thread -> node n_l = t>>3, cols j = (t&7)*4 + jj*32
    const int n_l = t >> 3;
    const int n_g = nb + n_l;
#pragma unroll
    for (int jj = 0; jj < 4; ++jj) {
        int j = ((t & 7) << 2) + jj * 32;
        float4 rv = *(const float4*)&gates[n_l][j];
        float4 zv = *(const float4*)&gates[n_l][128 + j];
        float4 iv = *(const float4*)&gates[n_l][256 + j];
        float4 nv = *(const float4*)&gates[n_l][384 + j];
        float4 br4 = *(const float4*)&b_ih[j];
        float4 bz4 = *(const float4*)&b_ih[128 + j];
        float4 bin4 = *(const float4*)&b_ih[256 + j];
        float4 bhn4 = *(const float4*)&b_hh[256 + j];
        {
            float4 u = *(const float4*)&b_hh[j];
            br4.x += u.x; br4.y += u.y; br4.z += u.z; br4.w += u.w;
            u = *(const float4*)&b_hh[128 + j];
            bz4.x += u.x; bz4.y += u.y; bz4.z += u.z; bz4.w += u.w;
        }
        uint2 uh = *(const uint2*)&hH[(size_t)n_g * H + j];
        uint2 ul = *(const uint2*)&hL[(size_t)n_g * H + j];
        float ho[4];
        ho[0] = bf2f(uh.x & 0xffff) + bf2f(ul.x & 0xffff);
        ho[1] = bf2f(uh.x >> 16) + bf2f(ul.x >> 16);
        ho[2] = bf2f(uh.y & 0xffff) + bf2f(ul.y & 0xffff);
        ho[3] = bf2f(uh.y >> 16) + bf2f(ul.y >> 16);
        unsigned long long packH = 0, packL = 0;
#define EPI(C, IDX)                                                                  \
        {                                                                            \
            float r_ = sigmoidf_(rv.C + br4.C);                                      \
            float z_ = sigmoidf_(zv.C + bz4.C);                                      \
            float ng = tanhf(iv.C + bin4.C + r_ * (nv.C + bhn4.C));                  \
            float hn = (1.f - z_) * ng + z_ * ho[IDX];                               \
            unsigned short hb = f2bf(hn);                                            \
            unsigned short lb = f2bf(hn - bf2f(hb));                                 \
            packH |= ((unsigned long long)hb) << (16 * IDX);                         \
            packL |= ((unsigned long long)lb) << (16 * IDX);                         \
        }
        EPI(x, 0) EPI(y, 1) EPI(z, 2) EPI(w, 3)
#undef EPI
        *(unsigned long long*)&hH[(size_t)n_g * H + j] = packH;
        *(unsigned long long*)&hL[(size_t)n_g * H + j] = packL;
    }
}

// ---------------- final linear + relu + per-graph accumulation ----------------
__global__ __launch_bounds__(256) void k_out(const unsigned short* __restrict__ hH,
                                             const unsigned short* __restrict__ hL,
                                             const float* __restrict__ lw,
                                             const float* __restrict__ lb,
                                             const int* __restrict__ batch,
                                             float* __restrict__ unc,
                                             float* __restrict__ gsum,
                                             float* __restrict__ gcnt) {
    int t = threadIdx.x;
    int n = blockIdx.x * 4 + (t >> 6);
    int lane = t & 63;
    unsigned int uh = *(const unsigned int*)&hH[(size_t)n * H + lane * 2];
    unsigned int ul = *(const unsigned int*)&hL[(size_t)n * H + lane * 2];
    float h0 = bf2f(uh & 0xffff) + bf2f(ul & 0xffff);
    float h1 = bf2f(uh >> 16) + bf2f(ul >> 16);
    float2 wv = *(const float2*)&lw[lane * 2];
    float v = fmaxf(h0, 0.f) * wv.x + fmaxf(h1, 0.f) * wv.y;
#pragma unroll
    for (int off = 32; off >= 1; off >>= 1) v += __shfl_xor(v, off, 64);
    if (lane == 0) {
        float o = v + lb[0];
        unc[n] = o;
        int b = batch[n];
        atomicAdd(&gsum[b], o);
        atomicAdd(&gcnt[b], 1.0f);
    }
}

__global__ __launch_bounds__(256) void k_corr(const float* __restrict__ unc,
                                              const int* __restrict__ batch,
                                              const float* __restrict__ gsum,
                                              const float* __restrict__ gcnt,
                                              float* __restrict__ corr) {
    int n = blockIdx.x * 256 + threadIdx.x;
    if (n >= N_NODES) return;
    int b = batch[n];
    float mean = gsum[b] / fmaxf(gcnt[b], 1.0f);
    corr[n] = unc[n] - mean;
}

extern "C" void kernel_launch(void* const* d_in, const int* in_sizes, int n_in,
                              void* d_out, int out_size, void* d_ws, size_t ws_size,
                              hipStream_t stream) {
    const float* x      = (const float*)d_in[0];
    const int*   ei     = (const int*)d_in[1];
    const int*   batch  = (const int*)d_in[2];
    const float* W0     = (const float*)d_in[4];
    const float* conv_w = (const float*)d_in[5];
    const float* w_ih   = (const float*)d_in[6];
    const float* b_ih   = (const float*)d_in[7];
    const float* w_hh   = (const float*)d_in[8];
    const float* b_hh   = (const float*)d_in[9];
    const float* lin1_w = (const float*)d_in[10];
    const float* lin1_b = (const float*)d_in[11];

    float* out = (float*)d_out;
    float* ws  = (float*)d_ws;

    float* m    = ws;                       // NH floats
    float* gsum = ws + (size_t)NH;          // G
    float* gcnt = gsum + G_GRAPHS;          // G
    int*   deg    = (int*)(ws + NH + 128);
    int*   offs   = deg + N_NODES;          // N+1
    int*   cursor = offs + N_NODES + 1;
    int*   bsum   = cursor + N_NODES;
    int*   boff   = bsum + NBLK;
    int*   csr    = boff + NBLK;            // E
    // 16B-aligned ushort region
    unsigned short* aggH = (unsigned short*)(ws + NH + 128 + 1900200);
    unsigned short* aggL = aggH + (size_t)NH;
    unsigned short* hH   = aggL + (size_t)NH;
    unsigned short* hL   = hH + (size_t)NH;
    unsigned short* WfH  = hL + (size_t)NH;   // 131072
    unsigned short* WfL  = WfH + 131072;

    float* out_corr  = out;                         // [N]
    float* out_embed = out + N_NODES;               // [N*H]
    float* out_unc   = out + N_NODES + (size_t)NH;  // [N]

    hipMemsetAsync(gsum, 0, 2 * G_GRAPHS * sizeof(float), stream);
    hipMemsetAsync(deg, 0, N_NODES * sizeof(int), stream);

    k_prepw<<<64, 256, 0, stream>>>(w_ih, w_hh, WfH, WfL);
    k_embed<<<NH / 256, 256, 0, stream>>>(x, W0, hH, hL, out_embed);

    k_hist<<<(N_EDGES + 255) / 256, 256, 0, stream>>>(ei, deg);
    k_blocksum<<<NBLK, 256, 0, stream>>>(deg, bsum);
    k_topscan<<<1, 64, 0, stream>>>(bsum, boff);
    k_scanwrite<<<NBLK, 256, 0, stream>>>(deg, boff, offs, cursor);
    k_scatter<<<(N_EDGES + 255) / 256, 256, 0, stream>>>(ei, cursor, csr);

    for (int l = 0; l < L_LAYERS; ++l) {
        k_conv<<<N_NODES / 32, 256, 0, stream>>>(hH, hL, conv_w + (size_t)l * H * H, m);
        k_agg<<<N_NODES / 4, 256, 0, stream>>>(offs, csr, m, aggH, aggL);
        k_ggru<<<N_NODES / 32, 256, 0, stream>>>(aggH, aggL, hH, hL, WfH, WfL, b_ih, b_hh);
    }

    k_out<<<N_NODES / 4, 256, 0, stream>>>(hH, hL, lin1_w, lin1_b, batch, out_unc, gsum, gcnt);
    k_corr<<<(N_NODES + 255) / 256, 256, 0, stream>>>(out_unc, batch, gsum, gcnt, out_corr);
}

// Round 5
// 1689.234 us; speedup vs baseline: 9.2254x; 1.4986x over previous
//
#include <hip/hip_runtime.h>

#define N_NODES 100000
#define N_EDGES 1600000
#define F_IN 32
#define H 128
#define H3 384
#define L_LAYERS 4
#define G_GRAPHS 64
#define NH (N_NODES * H)
#define SCAN_BS 1024
#define NBLK ((N_NODES + SCAN_BS - 1) / SCAN_BS)

typedef short bfrag __attribute__((ext_vector_type(8)));   // 8 bf16 = 4 VGPR
typedef float facc __attribute__((ext_vector_type(4)));    // 4 fp32 acc
typedef unsigned short u16x8 __attribute__((ext_vector_type(8)));

__device__ __forceinline__ float sigmoidf_(float x) { return 1.0f / (1.0f + __expf(-x)); }
__device__ __forceinline__ float bf2f(unsigned int u) { return __uint_as_float(u << 16); }
__device__ __forceinline__ unsigned short f2bf(float f) {
    unsigned int b = __float_as_uint(f);
    return (unsigned short)((b + 0x7FFF + ((b >> 16) & 1)) >> 16);
}
__device__ __forceinline__ facc mfma16(bfrag a, bfrag b, facc c) {
    return __builtin_amdgcn_mfma_f32_16x16x32_bf16(a, b, c, 0, 0, 0);
}

// ---------------- embed: x_embed = sigmoid(x @ W0^T) -> split h + fp32 out ----------------
__global__ __launch_bounds__(256) void k_embed(const float* __restrict__ x,
                                               const float* __restrict__ W0,
                                               unsigned short* __restrict__ hH,
                                               unsigned short* __restrict__ hL,
                                               float* __restrict__ out_embed) {
    int g = blockIdx.x * 256 + threadIdx.x;  // [0, N*H)
    int n = g >> 7, jj = g & 127;
    const float4* xr = (const float4*)(x + n * F_IN);
    const float4* wr = (const float4*)(W0 + jj * F_IN);
    float acc = 0.f;
#pragma unroll
    for (int f4 = 0; f4 < F_IN / 4; ++f4) {
        float4 a = xr[f4], b = wr[f4];
        acc += a.x * b.x + a.y * b.y + a.z * b.z + a.w * b.w;
    }
    float v = sigmoidf_(acc);
    out_embed[g] = v;
    unsigned short hi = f2bf(v);
    hH[g] = hi;
    hL[g] = f2bf(v - bf2f(hi));
}

// ---------------- CSR build ----------------
__global__ __launch_bounds__(256) void k_hist(const int* __restrict__ ei, int* __restrict__ deg) {
    int e = blockIdx.x * 256 + threadIdx.x;
    if (e >= N_EDGES) return;
    atomicAdd(&deg[ei[N_EDGES + e]], 1);
}

__global__ __launch_bounds__(256) void k_blocksum(const int* __restrict__ deg, int* __restrict__ bsum) {
    int b = blockIdx.x, t = threadIdx.x;
    int base = b * SCAN_BS + t * 4;
    int s = 0;
#pragma unroll
    for (int i = 0; i < 4; ++i) {
        int idx = base + i;
        if (idx < N_NODES) s += deg[idx];
    }
#pragma unroll
    for (int off = 1; off < 64; off <<= 1) s += __shfl_xor(s, off, 64);
    __shared__ int wtot[4];
    if ((t & 63) == 0) wtot[t >> 6] = s;
    __syncthreads();
    if (t == 0) bsum[b] = wtot[0] + wtot[1] + wtot[2] + wtot[3];
}

__global__ void k_topscan(const int* __restrict__ bsum, int* __restrict__ boff) {
    if (threadIdx.x == 0 && blockIdx.x == 0) {
        int acc = 0;
        for (int i = 0; i < NBLK; ++i) { boff[i] = acc; acc += bsum[i]; }
    }
}

__global__ __launch_bounds__(256) void k_scanwrite(const int* __restrict__ deg,
                                                   const int* __restrict__ boff,
                                                   int* __restrict__ offs,
                                                   int* __restrict__ cursor) {
    int b = blockIdx.x, t = threadIdx.x;
    int base = b * SCAN_BS + t * 4;
    int v[4];
    int s = 0;
#pragma unroll
    for (int i = 0; i < 4; ++i) {
        int idx = base + i;
        v[i] = (idx < N_NODES) ? deg[idx] : 0;
        s += v[i];
    }
    int lane = t & 63, w = t >> 6;
    int inc = s;
#pragma unroll
    for (int off = 1; off < 64; off <<= 1) {
        int u = __shfl_up(inc, off, 64);
        if (lane >= off) inc += u;
    }
    __shared__ int wtot[4];
    if (lane == 63) wtot[w] = inc;
    __syncthreads();
    int wpre = 0;
#pragma unroll
    for (int i = 0; i < 4; ++i)
        if (i < w) wpre += wtot[i];
    int run = inc - s + wpre + boff[b];
#pragma unroll
    for (int i = 0; i < 4; ++i) {
        int idx = base + i;
        if (idx < N_NODES) { offs[idx] = run; cursor[idx] = run; run += v[i]; }
    }
    if (b == 0 && t == 0) offs[N_NODES] = N_EDGES;
}

__global__ __launch_bounds__(256) void k_scatter(const int* __restrict__ ei,
                                                 int* __restrict__ cursor,
                                                 int* __restrict__ csr) {
    int e = blockIdx.x * 256 + threadIdx.x;
    if (e >= N_EDGES) return;
    int d = ei[N_EDGES + e];
    int pos = atomicAdd(&cursor[d], 1);
    csr[pos] = ei[e];
}

// ---------------- prep: build gate weights W2[256][512] in fragment-major split bf16 ------
// cols: 0-127 r | 128-255 z | 256-383 i_n (k<128 only) | 384-511 h_n (k>=128 only)
// layout: flat[((kc*32 + ntg)*64 + lane)*8 + j]; k = kc*32 + (lane>>4)*8 + j; c = ntg*16 + (lane&15)
__global__ __launch_bounds__(256) void k_prepw(const float* __restrict__ w_ih,
                                               const float* __restrict__ w_hh,
                                               unsigned short* __restrict__ WfH,
                                               unsigned short* __restrict__ WfL) {
    int tid = blockIdx.x * 256 + threadIdx.x;  // [0, 16384)
    int kc = tid >> 11;
    int ntg = (tid >> 6) & 31;
    int l = tid & 63;
    int c = ntg * 16 + (l & 15);
    int g = c >> 7;
    int jg = c & 127;
#pragma unroll
    for (int j = 0; j < 8; ++j) {
        int k = kc * 32 + ((l >> 4) << 3) + j;
        float val;
        if (k < 128) {
            val = (g < 3) ? w_ih[(g * 128 + jg) * 128 + k] : 0.f;
        } else {
            int k2 = k - 128;
            if (g == 2) val = 0.f;
            else val = w_hh[((g == 3 ? 256 : g * 128) + jg) * 128 + k2];
        }
        unsigned short hi = f2bf(val);
        WfH[tid * 8 + j] = hi;
        WfL[tid * 8 + j] = f2bf(val - bf2f(hi));
    }
}

// ---------------- conv: m = h @ W (h reconstructed from split) ----------------
__global__ __launch_bounds__(256) void k_conv(const unsigned short* __restrict__ hH,
                                              const unsigned short* __restrict__ hL,
                                              const float* __restrict__ W,
                                              float* __restrict__ m) {
    __shared__ float hs[32][H];   // 16 KB
    __shared__ float Ws[32][H];   // 16 KB
    const int t = threadIdx.x;
    const int nb = blockIdx.x * 32;
    {
        const u16x8* sh = (const u16x8*)(hH + (size_t)nb * H);
        const u16x8* sl = (const u16x8*)(hL + (size_t)nb * H);
        float* fl = &hs[0][0];
#pragma unroll
        for (int i = 0; i < 2; ++i) {
            int idx = t + 256 * i;
            u16x8 vh = sh[idx], vl = sl[idx];
            float4 f0, f1;
            f0.x = bf2f(vh[0]) + bf2f(vl[0]);
            f0.y = bf2f(vh[1]) + bf2f(vl[1]);
            f0.z = bf2f(vh[2]) + bf2f(vl[2]);
            f0.w = bf2f(vh[3]) + bf2f(vl[3]);
            f1.x = bf2f(vh[4]) + bf2f(vl[4]);
            f1.y = bf2f(vh[5]) + bf2f(vl[5]);
            f1.z = bf2f(vh[6]) + bf2f(vl[6]);
            f1.w = bf2f(vh[7]) + bf2f(vl[7]);
            *(float4*)&fl[idx * 8] = f0;
            *(float4*)&fl[idx * 8 + 4] = f1;
        }
    }
    const int j0 = (t & 63) * 2;
    const int grp = t >> 6;
    float2 acc[8];
#pragma unroll
    for (int i = 0; i < 8; ++i) acc[i] = make_float2(0.f, 0.f);
    for (int kc = 0; kc < 4; ++kc) {
        __syncthreads();
        {
            float4* d1 = (float4*)&Ws[0][0];
            const float4* s1 = (const float4*)(W + kc * 32 * H);
#pragma unroll
            for (int i = 0; i < 4; ++i) d1[t + 256 * i] = s1[t + 256 * i];
        }
        __syncthreads();
#pragma unroll
        for (int kk = 0; kk < 32; ++kk) {
            int k = kc * 32 + kk;
            float2 w = *(const float2*)&Ws[kk][j0];
#pragma unroll
            for (int i = 0; i < 8; ++i) {
                float hv = hs[grp + 4 * i][k];
                acc[i].x += hv * w.x;
                acc[i].y += hv * w.y;
            }
        }
    }
#pragma unroll
    for (int i = 0; i < 8; ++i) {
        *(float2*)&m[(size_t)(nb + grp + 4 * i) * H + j0] = acc[i];
    }
}

// ---------------- aggregate: agg[n] = sum_{in-edges} m[src]; emit split bf16 ----------
__global__ __launch_bounds__(256) void k_agg(const int* __restrict__ offs,
                                             const int* __restrict__ csr,
                                             const float* __restrict__ m,
                                             unsigned short* __restrict__ aggH,
                                             unsigned short* __restrict__ aggL) {
    int t = threadIdx.x;
    int n = blockIdx.x * 4 + (t >> 6);
    int lane = t & 63;
    int beg = offs[n], end = offs[n + 1];
    float2 acc = make_float2(0.f, 0.f);
    int i = beg;
    for (; i + 1 < end; i += 2) {
        int s0 = csr[i], s1 = csr[i + 1];
        float2 a = *(const float2*)&m[(size_t)s0 * H + lane * 2];
        float2 b = *(const float2*)&m[(size_t)s1 * H + lane * 2];
        acc.x += a.x + b.x;
        acc.y += a.y + b.y;
    }
    if (i < end) {
        float2 a = *(const float2*)&m[(size_t)csr[i] * H + lane * 2];
        acc.x += a.x;
        acc.y += a.y;
    }
    unsigned short hx = f2bf(acc.x);
    unsigned short lx = f2bf(acc.x - bf2f(hx));
    unsigned short hy = f2bf(acc.y);
    unsigned short ly = f2bf(acc.y - bf2f(hy));
    *(unsigned int*)&aggH[(size_t)n * H + lane * 2] = (unsigned int)hx | ((unsigned int)hy << 16);
    *(unsigned int*)&aggL[(size_t)n * H + lane * 2] = (unsigned int)lx | ((unsigned int)ly << 16);
}

// ---------------- fused MFMA gates GEMM + GRU epilogue ----------------
// block: 32 rows x 512 cols; 4 waves, each 32r x 128c (2 mtiles x 8 ntiles)
__global__ __launch_bounds__(256, 2) void k_ggru(const unsigned short* __restrict__ aggH,
                                                 const unsigned short* __restrict__ aggL,
                                                 unsigned short* __restrict__ hH,
                                                 unsigned short* __restrict__ hL,
                                                 const unsigned short* __restrict__ WfH,
                                                 const unsigned short* __restrict__ WfL,
                                                 const float* __restrict__ b_ih,
                                                 const float* __restrict__ b_hh) {
    __shared__ short Ast[2][2][64][8];   // [hi/lo][mtile][lane][8] = 4 KB
    __shared__ float gates[32][516];     // 64.5 KB (pad 516 kills epilogue bank conflicts)
    const int t = threadIdx.x;
    const int wv = t >> 6, l = t & 63;
    const int nb = blockIdx.x * 32;

    facc acc[2][8];
#pragma unroll
    for (int mt = 0; mt < 2; ++mt)
#pragma unroll
        for (int nt = 0; nt < 8; ++nt) acc[mt][nt] = (facc)(0.f);

    // staging role: wave wv stages (part = wv>>1 [hi/lo], mt_s = wv&1)
    const int part = wv >> 1, mt_s = wv & 1;
    const int srow = nb + mt_s * 16 + (l & 15);
    const int kb8 = (l >> 4) << 3;
    const unsigned short* aggP = part ? aggL : aggH;
    const unsigned short* hP = part ? hL : hH;

    // B fragment base (fragment-major prepped)
    const short* pBH = (const short*)WfH + (wv * 512 + l) * 8;
    const short* pBL = (const short*)WfL + (wv * 512 + l) * 8;

    bfrag sA = *(const bfrag*)(aggP + (size_t)srow * H + kb8);  // kc=0
    for (int kc = 0; kc < 8; ++kc) {
        __syncthreads();  // prior reads of Ast done
        *(bfrag*)&Ast[part][mt_s][l][0] = sA;
        if (kc < 7) {
            int kn = kc + 1;
            const unsigned short* base = (kn < 4) ? aggP : hP;
            sA = *(const bfrag*)(base + (size_t)srow * H + ((kn & 3) << 5) + kb8);
        }
        __syncthreads();
        bfrag a0h = *(const bfrag*)&Ast[0][0][l][0];
        bfrag a1h = *(const bfrag*)&Ast[0][1][l][0];
        bfrag a0l = *(const bfrag*)&Ast[1][0][l][0];
        bfrag a1l = *(const bfrag*)&Ast[1][1][l][0];
        const short* bh = pBH + kc * 16384;
        const short* bl = pBL + kc * 16384;
#pragma unroll
        for (int nt = 0; nt < 8; ++nt) {
            bfrag wH = *(const bfrag*)(bh + nt * 512);
            bfrag wL = *(const bfrag*)(bl + nt * 512);
            acc[0][nt] = mfma16(a0h, wH, acc[0][nt]);
            acc[0][nt] = mfma16(a0h, wL, acc[0][nt]);
            acc[0][nt] = mfma16(a0l, wH, acc[0][nt]);
            acc[1][nt] = mfma16(a1h, wH, acc[1][nt]);
            acc[1][nt] = mfma16(a1h, wL, acc[1][nt]);
            acc[1][nt] = mfma16(a1l, wH, acc[1][nt]);
        }
    }

    // acc -> gates LDS.  C/D layout: col = lane&15, row = (lane>>4)*4 + reg
#pragma unroll
    for (int mt = 0; mt < 2; ++mt)
#pragma unroll
        for (int nt = 0; nt < 8; ++nt) {
            int r0 = mt * 16 + ((l >> 4) << 2);
            int c = wv * 128 + nt * 16 + (l & 15);
#pragma unroll
            for (int reg = 0; reg < 4; ++reg) gates[r0 + reg][c] = acc[mt][nt][reg];
        }
    __syncthreads();

    // GRU epilogue: thread -> node n_l = t>>3, cols j = (t&7)*4 + jj*32
    const int n_l = t >> 3;
    const int n_g = nb + n_l;
#pragma unroll
    for (int jj = 0; jj < 4; ++jj) {
        int j = ((t & 7) << 2) + jj * 32;
        float4 rv = *(const float4*)&gates[n_l][j];
        float4 zv = *(const float4*)&gates[n_l][128 + j];
        float4 iv = *(const float4*)&gates[n_l][256 + j];
        float4 nv = *(const float4*)&gates[n_l][384 + j];
        float4 br4 = *(const float4*)&b_ih[j];
        float4 bz4 = *(const float4*)&b_ih[128 + j];
        float4 bin4 = *(const float4*)&b_ih[256 + j];
        float4 bhn4 = *(const float4*)&b_hh[256 + j];
        {
            float4 u = *(const float4*)&b_hh[j];
            br4.x += u.x; br4.y += u.y; br4.z += u.z; br4.w += u.w;
            u = *(const float4*)&b_hh[128 + j];
            bz4.x += u.x; bz4.y += u.y; bz4.z += u.z; bz4.w += u.w;
        }
        uint2 uh = *(const uint2*)&hH[(size_t)n_g * H + j];
        uint2 ul = *(const uint2*)&hL[(size_t)n_g * H + j];
        float ho[4];
        ho[0] = bf2f(uh.x & 0xffff) + bf2f(ul.x & 0xffff);
        ho[1] = bf2f(uh.x >> 16) + bf2f(ul.x >> 16);
        ho[2] = bf2f(uh.y & 0xffff) + bf2f(ul.y & 0xffff);
        ho[3] = bf2f(uh.y >> 16) + bf2f(ul.y >> 16);
        unsigned long long packH = 0, packL = 0;
#define EPI(C, IDX)                                                                  \
        {                                                                            \
            float r_ = sigmoidf_(rv.C + br4.C);                                      \
            float z_ = sigmoidf_(zv.C + bz4.C);                                      \
            float ng = tanhf(iv.C + bin4.C + r_ * (nv.C + bhn4.C));                  \
            float hn = (1.f - z_) * ng + z_ * ho[IDX];                               \
            unsigned short hb = f2bf(hn);                                            \
            unsigned short lb = f2bf(hn - bf2f(hb));                                 \
            packH |= ((unsigned long long)hb) << (16 * IDX);                         \
            packL |= ((unsigned long long)lb) << (16 * IDX);                         \
        }
        EPI(x, 0) EPI(y, 1) EPI(z, 2) EPI(w, 3)
#undef EPI
        *(unsigned long long*)&hH[(size_t)n_g * H + j] = packH;
        *(unsigned long long*)&hL[(size_t)n_g * H + j] = packL;
    }
}

// ---------------- final linear + relu + LDS-staged per-graph accumulation ----------------
// block = 256 threads = 4 node-groups; 16 iterations -> 64 nodes/block.
// Per-graph partials in LDS, then <=64 global atomics/block (batch sorted -> ~2 graphs/block).
__global__ __launch_bounds__(256) void k_out(const unsigned short* __restrict__ hH,
                                             const unsigned short* __restrict__ hL,
                                             const float* __restrict__ lw,
                                             const float* __restrict__ lb,
                                             const int* __restrict__ batch,
                                             float* __restrict__ unc,
                                             float* __restrict__ gsum,
                                             float* __restrict__ gcnt) {
    __shared__ float sgs[G_GRAPHS];
    __shared__ float sgc[G_GRAPHS];
    const int t = threadIdx.x;
    if (t < G_GRAPHS) { sgs[t] = 0.f; sgc[t] = 0.f; }
    __syncthreads();
    const int lane = t & 63;
    const int grp = t >> 6;
    const float2 wv = *(const float2*)&lw[lane * 2];
    const float lbv = lb[0];
    const int base = blockIdx.x * 64;
#pragma unroll 4
    for (int it = 0; it < 16; ++it) {
        int n = base + it * 4 + grp;
        if (n < N_NODES) {
            unsigned int uh = *(const unsigned int*)&hH[(size_t)n * H + lane * 2];
            unsigned int ul = *(const unsigned int*)&hL[(size_t)n * H + lane * 2];
            float h0 = bf2f(uh & 0xffff) + bf2f(ul & 0xffff);
            float h1 = bf2f(uh >> 16) + bf2f(ul >> 16);
            float v = fmaxf(h0, 0.f) * wv.x + fmaxf(h1, 0.f) * wv.y;
#pragma unroll
            for (int off = 32; off >= 1; off >>= 1) v += __shfl_xor(v, off, 64);
            if (lane == 0) {
                float o = v + lbv;
                unc[n] = o;
                int b = batch[n];
                atomicAdd(&sgs[b], o);
                atomicAdd(&sgc[b], 1.0f);
            }
        }
    }
    __syncthreads();
    if (t < G_GRAPHS && sgc[t] != 0.f) {
        atomicAdd(&gsum[t], sgs[t]);
        atomicAdd(&gcnt[t], sgc[t]);
    }
}

__global__ __launch_bounds__(256) void k_corr(const float* __restrict__ unc,
                                              const int* __restrict__ batch,
                                              const float* __restrict__ gsum,
                                              const float* __restrict__ gcnt,
                                              float* __restrict__ corr) {
    int n = blockIdx.x * 256 + threadIdx.x;
    if (n >= N_NODES) return;
    int b = batch[n];
    float mean = gsum[b] / fmaxf(gcnt[b], 1.0f);
    corr[n] = unc[n] - mean;
}

extern "C" void kernel_launch(void* const* d_in, const int* in_sizes, int n_in,
                              void* d_out, int out_size, void* d_ws, size_t ws_size,
                              hipStream_t stream) {
    const float* x      = (const float*)d_in[0];
    const int*   ei     = (const int*)d_in[1];
    const int*   batch  = (const int*)d_in[2];
    const float* W0     = (const float*)d_in[4];
    const float* conv_w = (const float*)d_in[5];
    const float* w_ih   = (const float*)d_in[6];
    const float* b_ih   = (const float*)d_in[7];
    const float* w_hh   = (const float*)d_in[8];
    const float* b_hh   = (const float*)d_in[9];
    const float* lin1_w = (const float*)d_in[10];
    const float* lin1_b = (const float*)d_in[11];

    float* out = (float*)d_out;
    float* ws  = (float*)d_ws;

    float* m    = ws;                       // NH floats
    float* gsum = ws + (size_t)NH;          // G
    float* gcnt = gsum + G_GRAPHS;          // G
    int*   deg    = (int*)(ws + NH + 128);
    int*   offs   = deg + N_NODES;          // N+1
    int*   cursor = offs + N_NODES + 1;
    int*   bsum   = cursor + N_NODES;
    int*   boff   = bsum + NBLK;
    int*   csr    = boff + NBLK;            // E
    // 16B-aligned ushort region
    unsigned short* aggH = (unsigned short*)(ws + NH + 128 + 1900200);
    unsigned short* aggL = aggH + (size_t)NH;
    unsigned short* hH   = aggL + (size_t)NH;
    unsigned short* hL   = hH + (size_t)NH;
    unsigned short* WfH  = hL + (size_t)NH;   // 131072
    unsigned short* WfL  = WfH + 131072;

    float* out_corr  = out;                         // [N]
    float* out_embed = out + N_NODES;               // [N*H]
    float* out_unc   = out + N_NODES + (size_t)NH;  // [N]

    hipMemsetAsync(gsum, 0, 2 * G_GRAPHS * sizeof(float), stream);
    hipMemsetAsync(deg, 0, N_NODES * sizeof(int), stream);

    k_prepw<<<64, 256, 0, stream>>>(w_ih, w_hh, WfH, WfL);
    k_embed<<<NH / 256, 256, 0, stream>>>(x, W0, hH, hL, out_embed);

    k_hist<<<(N_EDGES + 255) / 256, 256, 0, stream>>>(ei, deg);
    k_blocksum<<<NBLK, 256, 0, stream>>>(deg, bsum);
    k_topscan<<<1, 64, 0, stream>>>(bsum, boff);
    k_scanwrite<<<NBLK, 256, 0, stream>>>(deg, boff, offs, cursor);
    k_scatter<<<(N_EDGES + 255) / 256, 256, 0, stream>>>(ei, cursor, csr);

    for (int l = 0; l < L_LAYERS; ++l) {
        k_conv<<<N_NODES / 32, 256, 0, stream>>>(hH, hL, conv_w + (size_t)l * H * H, m);
        k_agg<<<N_NODES / 4, 256, 0, stream>>>(offs, csr, m, aggH, aggL);
        k_ggru<<<N_NODES / 32, 256, 0, stream>>>(aggH, aggL, hH, hL, WfH, WfL, b_ih, b_hh);
    }

    k_out<<<(N_NODES + 63) / 64, 256, 0, stream>>>(hH, hL, lin1_w, lin1_b, batch, out_unc, gsum, gcnt);
    k_corr<<<(N_NODES + 255) / 256, 256, 0, stream>>>(out_unc, batch, gsum, gcnt, out_corr);
}

// Round 6
// 1414.914 us; speedup vs baseline: 11.0140x; 1.1939x over previous
//
#include <hip/hip_runtime.h>

#define N_NODES 100000
#define N_EDGES 1600000
#define F_IN 32
#define H 128
#define H3 384
#define L_LAYERS 4
#define G_GRAPHS 64
#define NH (N_NODES * H)
#define SCAN_BS 1024
#define NBLK ((N_NODES + SCAN_BS - 1) / SCAN_BS)

typedef short bfrag __attribute__((ext_vector_type(8)));   // 8 bf16 = 4 VGPR
typedef float facc __attribute__((ext_vector_type(4)));    // 4 fp32 acc
typedef unsigned short u16x8 __attribute__((ext_vector_type(8)));

__device__ __forceinline__ float sigmoidf_(float x) { return 1.0f / (1.0f + __expf(-x)); }
__device__ __forceinline__ float bf2f(unsigned int u) { return __uint_as_float(u << 16); }
__device__ __forceinline__ unsigned short f2bf(float f) {
    unsigned int b = __float_as_uint(f);
    return (unsigned short)((b + 0x7FFF + ((b >> 16) & 1)) >> 16);
}
__device__ __forceinline__ facc mfma16(bfrag a, bfrag b, facc c) {
    return __builtin_amdgcn_mfma_f32_16x16x32_bf16(a, b, c, 0, 0, 0);
}

// ---------------- prep: W0T[32][128] = W0[j][k] transposed (once per call) ----------------
__global__ __launch_bounds__(256) void k_prepw0(const float* __restrict__ W0,
                                                float* __restrict__ W0T) {
    int tid = blockIdx.x * 256 + threadIdx.x;  // [0, 4096)
    int k = tid >> 7, j = tid & 127;
    W0T[tid] = W0[j * F_IN + k];
}

// ---------------- embed: 64 nodes/block, LDS-tiled, vectorized writes ----------------
__global__ __launch_bounds__(256) void k_embed(const float* __restrict__ x,
                                               const float* __restrict__ W0T,
                                               unsigned short* __restrict__ hH,
                                               unsigned short* __restrict__ hL,
                                               float* __restrict__ out_embed) {
    __shared__ float w0s[32][128];  // 16 KB, W0T staged
    __shared__ float xsT[32][64];   // 8 KB, x tile transposed: xsT[k][n_l]
    const int t = threadIdx.x;
    const int nb = blockIdx.x * 64;
    {
        float4* d = (float4*)&w0s[0][0];
        const float4* s = (const float4*)W0T;
#pragma unroll
        for (int i = 0; i < 4; ++i) d[t + 256 * i] = s[t + 256 * i];
    }
    {
        int n_l = t >> 2, k0 = (t & 3) * 8;
        int n = nb + n_l;
        float4 a = make_float4(0.f, 0.f, 0.f, 0.f), b = a;
        if (n < N_NODES) {
            a = *(const float4*)&x[(size_t)n * F_IN + k0];
            b = *(const float4*)&x[(size_t)n * F_IN + k0 + 4];
        }
        xsT[k0 + 0][n_l] = a.x; xsT[k0 + 1][n_l] = a.y;
        xsT[k0 + 2][n_l] = a.z; xsT[k0 + 3][n_l] = a.w;
        xsT[k0 + 4][n_l] = b.x; xsT[k0 + 5][n_l] = b.y;
        xsT[k0 + 6][n_l] = b.z; xsT[k0 + 7][n_l] = b.w;
    }
    __syncthreads();
    const int n0 = (t >> 5) * 8;   // 8 nodes per thread
    const int j0 = (t & 31) * 4;   // 4 cols per thread
    float4 acc[8];
#pragma unroll
    for (int i = 0; i < 8; ++i) acc[i] = make_float4(0.f, 0.f, 0.f, 0.f);
#pragma unroll 8
    for (int k = 0; k < 32; ++k) {
        float4 w = *(const float4*)&w0s[k][j0];
        float4 va = *(const float4*)&xsT[k][n0];
        float4 vb = *(const float4*)&xsT[k][n0 + 4];
        float xv[8] = {va.x, va.y, va.z, va.w, vb.x, vb.y, vb.z, vb.w};
#pragma unroll
        for (int i = 0; i < 8; ++i) {
            acc[i].x = fmaf(xv[i], w.x, acc[i].x);
            acc[i].y = fmaf(xv[i], w.y, acc[i].y);
            acc[i].z = fmaf(xv[i], w.z, acc[i].z);
            acc[i].w = fmaf(xv[i], w.w, acc[i].w);
        }
    }
#pragma unroll
    for (int i = 0; i < 8; ++i) {
        int n = nb + n0 + i;
        if (n < N_NODES) {
            float4 v;
            v.x = sigmoidf_(acc[i].x); v.y = sigmoidf_(acc[i].y);
            v.z = sigmoidf_(acc[i].z); v.w = sigmoidf_(acc[i].w);
            *(float4*)&out_embed[(size_t)n * H + j0] = v;
            unsigned short h0 = f2bf(v.x), h1 = f2bf(v.y), h2 = f2bf(v.z), h3 = f2bf(v.w);
            unsigned short l0 = f2bf(v.x - bf2f(h0)), l1 = f2bf(v.y - bf2f(h1));
            unsigned short l2 = f2bf(v.z - bf2f(h2)), l3 = f2bf(v.w - bf2f(h3));
            uint2 ph, pl;
            ph.x = (unsigned int)h0 | ((unsigned int)h1 << 16);
            ph.y = (unsigned int)h2 | ((unsigned int)h3 << 16);
            pl.x = (unsigned int)l0 | ((unsigned int)l1 << 16);
            pl.y = (unsigned int)l2 | ((unsigned int)l3 << 16);
            *(uint2*)&hH[(size_t)n * H + j0] = ph;
            *(uint2*)&hL[(size_t)n * H + j0] = pl;
        }
    }
}

// ---------------- CSR build ----------------
__global__ __launch_bounds__(256) void k_hist(const int* __restrict__ ei, int* __restrict__ deg) {
    int e = blockIdx.x * 256 + threadIdx.x;
    if (e >= N_EDGES) return;
    atomicAdd(&deg[ei[N_EDGES + e]], 1);
}

__global__ __launch_bounds__(256) void k_blocksum(const int* __restrict__ deg, int* __restrict__ bsum) {
    int b = blockIdx.x, t = threadIdx.x;
    int base = b * SCAN_BS + t * 4;
    int s = 0;
#pragma unroll
    for (int i = 0; i < 4; ++i) {
        int idx = base + i;
        if (idx < N_NODES) s += deg[idx];
    }
#pragma unroll
    for (int off = 1; off < 64; off <<= 1) s += __shfl_xor(s, off, 64);
    __shared__ int wtot[4];
    if ((t & 63) == 0) wtot[t >> 6] = s;
    __syncthreads();
    if (t == 0) bsum[b] = wtot[0] + wtot[1] + wtot[2] + wtot[3];
}

__global__ void k_topscan(const int* __restrict__ bsum, int* __restrict__ boff) {
    if (threadIdx.x == 0 && blockIdx.x == 0) {
        int acc = 0;
        for (int i = 0; i < NBLK; ++i) { boff[i] = acc; acc += bsum[i]; }
    }
}

__global__ __launch_bounds__(256) void k_scanwrite(const int* __restrict__ deg,
                                                   const int* __restrict__ boff,
                                                   int* __restrict__ offs,
                                                   int* __restrict__ cursor) {
    int b = blockIdx.x, t = threadIdx.x;
    int base = b * SCAN_BS + t * 4;
    int v[4];
    int s = 0;
#pragma unroll
    for (int i = 0; i < 4; ++i) {
        int idx = base + i;
        v[i] = (idx < N_NODES) ? deg[idx] : 0;
        s += v[i];
    }
    int lane = t & 63, w = t >> 6;
    int inc = s;
#pragma unroll
    for (int off = 1; off < 64; off <<= 1) {
        int u = __shfl_up(inc, off, 64);
        if (lane >= off) inc += u;
    }
    __shared__ int wtot[4];
    if (lane == 63) wtot[w] = inc;
    __syncthreads();
    int wpre = 0;
#pragma unroll
    for (int i = 0; i < 4; ++i)
        if (i < w) wpre += wtot[i];
    int run = inc - s + wpre + boff[b];
#pragma unroll
    for (int i = 0; i < 4; ++i) {
        int idx = base + i;
        if (idx < N_NODES) { offs[idx] = run; cursor[idx] = run; run += v[i]; }
    }
    if (b == 0 && t == 0) offs[N_NODES] = N_EDGES;
}

__global__ __launch_bounds__(256) void k_scatter(const int* __restrict__ ei,
                                                 int* __restrict__ cursor,
                                                 int* __restrict__ csr) {
    int e = blockIdx.x * 256 + threadIdx.x;
    if (e >= N_EDGES) return;
    int d = ei[N_EDGES + e];
    int pos = atomicAdd(&cursor[d], 1);
    csr[pos] = ei[e];
}

// ---------------- prep: GRU gate weights W2[256][512] fragment-major split bf16 ----------
__global__ __launch_bounds__(256) void k_prepw(const float* __restrict__ w_ih,
                                               const float* __restrict__ w_hh,
                                               unsigned short* __restrict__ WfH,
                                               unsigned short* __restrict__ WfL) {
    int tid = blockIdx.x * 256 + threadIdx.x;  // [0, 16384)
    int kc = tid >> 11;
    int ntg = (tid >> 6) & 31;
    int l = tid & 63;
    int c = ntg * 16 + (l & 15);
    int g = c >> 7;
    int jg = c & 127;
#pragma unroll
    for (int j = 0; j < 8; ++j) {
        int k = kc * 32 + ((l >> 4) << 3) + j;
        float val;
        if (k < 128) {
            val = (g < 3) ? w_ih[(g * 128 + jg) * 128 + k] : 0.f;
        } else {
            int k2 = k - 128;
            if (g == 2) val = 0.f;
            else val = w_hh[((g == 3 ? 256 : g * 128) + jg) * 128 + k2];
        }
        unsigned short hi = f2bf(val);
        WfH[tid * 8 + j] = hi;
        WfL[tid * 8 + j] = f2bf(val - bf2f(hi));
    }
}

// ---------------- prep: conv weights [L][128][128] fragment-major split bf16 ----------
// per layer: flat[((kc*8 + ntg)*64 + lane)*8 + j]; k = kc*32+(lane>>4)*8+j; c = ntg*16+(lane&15)
__global__ __launch_bounds__(256) void k_prepcw(const float* __restrict__ conv_w,
                                                unsigned short* __restrict__ WcH,
                                                unsigned short* __restrict__ WcL) {
    int tid = blockIdx.x * 256 + threadIdx.x;  // [0, 8192)
    int lyr = tid >> 11;
    int rem = tid & 2047;
    int kc = rem >> 9;
    int ntg = (rem >> 6) & 7;
    int l = rem & 63;
    int c = ntg * 16 + (l & 15);
#pragma unroll
    for (int j = 0; j < 8; ++j) {
        int k = kc * 32 + ((l >> 4) << 3) + j;
        float val = conv_w[(size_t)lyr * H * H + k * H + c];
        unsigned short hi = f2bf(val);
        WcH[tid * 8 + j] = hi;
        WcL[tid * 8 + j] = f2bf(val - bf2f(hi));
    }
}

// ---------------- conv (MFMA): m = h @ conv_w[l], split-bf16 3-term ----------------
// block: 32 rows x 128 cols; 4 waves, each 32r x 32c (2 mtiles x 2 ntiles)
__global__ __launch_bounds__(256) void k_conv(const unsigned short* __restrict__ hH,
                                              const unsigned short* __restrict__ hL,
                                              const unsigned short* __restrict__ WcH,
                                              const unsigned short* __restrict__ WcL,
                                              float* __restrict__ m) {
    __shared__ short Ast[2][2][64][8];   // [hi/lo][mtile][lane][8] = 4 KB
    const int t = threadIdx.x;
    const int wv = t >> 6, l = t & 63;
    const int nb = blockIdx.x * 32;

    facc acc[2][2];
#pragma unroll
    for (int mt = 0; mt < 2; ++mt)
#pragma unroll
        for (int nt = 0; nt < 2; ++nt) acc[mt][nt] = (facc)(0.f);

    const int part = wv >> 1, mt_s = wv & 1;
    const int srow = nb + mt_s * 16 + (l & 15);
    const int kb8 = (l >> 4) << 3;
    const unsigned short* hP = part ? hL : hH;

    bfrag sA = *(const bfrag*)(hP + (size_t)srow * H + kb8);  // kc=0
    for (int kc = 0; kc < 4; ++kc) {
        __syncthreads();
        *(bfrag*)&Ast[part][mt_s][l][0] = sA;
        if (kc < 3) sA = *(const bfrag*)(hP + (size_t)srow * H + (kc + 1) * 32 + kb8);
        __syncthreads();
        bfrag a0h = *(const bfrag*)&Ast[0][0][l][0];
        bfrag a1h = *(const bfrag*)&Ast[0][1][l][0];
        bfrag a0l = *(const bfrag*)&Ast[1][0][l][0];
        bfrag a1l = *(const bfrag*)&Ast[1][1][l][0];
#pragma unroll
        for (int nt = 0; nt < 2; ++nt) {
            int ntg = wv * 2 + nt;
            const short* bh = (const short*)WcH + (size_t)((kc * 8 + ntg) * 64 + l) * 8;
            const short* bl = (const short*)WcL + (size_t)((kc * 8 + ntg) * 64 + l) * 8;
            bfrag wH = *(const bfrag*)bh;
            bfrag wL = *(const bfrag*)bl;
            acc[0][nt] = mfma16(a0h, wH, acc[0][nt]);
            acc[0][nt] = mfma16(a0h, wL, acc[0][nt]);
            acc[0][nt] = mfma16(a0l, wH, acc[0][nt]);
            acc[1][nt] = mfma16(a1h, wH, acc[1][nt]);
            acc[1][nt] = mfma16(a1h, wL, acc[1][nt]);
            acc[1][nt] = mfma16(a1l, wH, acc[1][nt]);
        }
    }
#pragma unroll
    for (int mt = 0; mt < 2; ++mt)
#pragma unroll
        for (int nt = 0; nt < 2; ++nt) {
            int r0 = mt * 16 + ((l >> 4) << 2);
            int c = wv * 32 + nt * 16 + (l & 15);
#pragma unroll
            for (int reg = 0; reg < 4; ++reg)
                m[(size_t)(nb + r0 + reg) * H + c] = acc[mt][nt][reg];
        }
}

// ---------------- aggregate: agg[n] = sum_{in-edges} m[src]; emit split bf16 ----------
__global__ __launch_bounds__(256) void k_agg(const int* __restrict__ offs,
                                             const int* __restrict__ csr,
                                             const float* __restrict__ m,
                                             unsigned short* __restrict__ aggH,
                                             unsigned short* __restrict__ aggL) {
    int t = threadIdx.x;
    int n = blockIdx.x * 4 + (t >> 6);
    int lane = t & 63;
    int beg = offs[n], end = offs[n + 1];
    float2 acc = make_float2(0.f, 0.f);
    int i = beg;
    for (; i + 1 < end; i += 2) {
        int s0 = csr[i], s1 = csr[i + 1];
        float2 a = *(const float2*)&m[(size_t)s0 * H + lane * 2];
        float2 b = *(const float2*)&m[(size_t)s1 * H + lane * 2];
        acc.x += a.x + b.x;
        acc.y += a.y + b.y;
    }
    if (i < end) {
        float2 a = *(const float2*)&m[(size_t)csr[i] * H + lane * 2];
        acc.x += a.x;
        acc.y += a.y;
    }
    unsigned short hx = f2bf(acc.x);
    unsigned short lx = f2bf(acc.x - bf2f(hx));
    unsigned short hy = f2bf(acc.y);
    unsigned short ly = f2bf(acc.y - bf2f(hy));
    *(unsigned int*)&aggH[(size_t)n * H + lane * 2] = (unsigned int)hx | ((unsigned int)hy << 16);
    *(unsigned int*)&aggL[(size_t)n * H + lane * 2] = (unsigned int)lx | ((unsigned int)ly << 16);
}

// ---------------- fused MFMA gates GEMM + GRU epilogue ----------------
__global__ __launch_bounds__(256, 2) void k_ggru(const unsigned short* __restrict__ aggH,
                                                 const unsigned short* __restrict__ aggL,
                                                 unsigned short* __restrict__ hH,
                                                 unsigned short* __restrict__ hL,
                                                 const unsigned short* __restrict__ WfH,
                                                 const unsigned short* __restrict__ WfL,
                                                 const float* __restrict__ b_ih,
                                                 const float* __restrict__ b_hh) {
    __shared__ short Ast[2][2][64][8];   // 4 KB
    __shared__ float gates[32][516];     // 64.5 KB
    const int t = threadIdx.x;
    const int wv = t >> 6, l = t & 63;
    const int nb = blockIdx.x * 32;

    facc acc[2][8];
#pragma unroll
    for (int mt = 0; mt < 2; ++mt)
#pragma unroll
        for (int nt = 0; nt < 8; ++nt) acc[mt][nt] = (facc)(0.f);

    const int part = wv >> 1, mt_s = wv & 1;
    const int srow = nb + mt_s * 16 + (l & 15);
    const int kb8 = (l >> 4) << 3;
    const unsigned short* aggP = part ? aggL : aggH;
    const unsigned short* hP = part ? hL : hH;

    const short* pBH = (const short*)WfH + (wv * 512 + l) * 8;
    const short* pBL = (const short*)WfL + (wv * 512 + l) * 8;

    bfrag sA = *(const bfrag*)(aggP + (size_t)srow * H + kb8);  // kc=0
    for (int kc = 0; kc < 8; ++kc) {
        __syncthreads();
        *(bfrag*)&Ast[part][mt_s][l][0] = sA;
        if (kc < 7) {
            int kn = kc + 1;
            const unsigned short* base = (kn < 4) ? aggP : hP;
            sA = *(const bfrag*)(base + (size_t)srow * H + ((kn & 3) << 5) + kb8);
        }
        __syncthreads();
        bfrag a0h = *(const bfrag*)&Ast[0][0][l][0];
        bfrag a1h = *(const bfrag*)&Ast[0][1][l][0];
        bfrag a0l = *(const bfrag*)&Ast[1][0][l][0];
        bfrag a1l = *(const bfrag*)&Ast[1][1][l][0];
        const short* bh = pBH + kc * 16384;
        const short* bl = pBL + kc * 16384;
#pragma unroll
        for (int nt = 0; nt < 8; ++nt) {
            bfrag wH = *(const bfrag*)(bh + nt * 512);
            bfrag wL = *(const bfrag*)(bl + nt * 512);
            acc[0][nt] = mfma16(a0h, wH, acc[0][nt]);
            acc[0][nt] = mfma16(a0h, wL, acc[0][nt]);
            acc[0][nt] = mfma16(a0l, wH, acc[0][nt]);
            acc[1][nt] = mfma16(a1h, wH, acc[1][nt]);
            acc[1][nt] = mfma16(a1h, wL, acc[1][nt]);
            acc[1][nt] = mfma16(a1l, wH, acc[1][nt]);
        }
    }

#pragma unroll
    for (int mt = 0; mt < 2; ++mt)
#pragma unroll
        for (int nt = 0; nt < 8; ++nt) {
            int r0 = mt * 16 + ((l >> 4) << 2);
            int c = wv * 128 + nt * 16 + (l & 15);
#pragma unroll
            for (int reg = 0; reg < 4; ++reg) gates[r0 + reg][c] = acc[mt][nt][reg];
        }
    __syncthreads();

    const int n_l = t >> 3;
    const int n_g = nb + n_l;
#pragma unroll
    for (int jj = 0; jj < 4; ++jj) {
        int j = ((t & 7) << 2) + jj * 32;
        float4 rv = *(const float4*)&gates[n_l][j];
        float4 zv = *(const float4*)&gates[n_l][128 + j];
        float4 iv = *(const float4*)&gates[n_l][256 + j];
        float4 nv = *(const float4*)&gates[n_l][384 + j];
        float4 br4 = *(const float4*)&b_ih[j];
        float4 bz4 = *(const float4*)&b_ih[128 + j];
        float4 bin4 = *(const float4*)&b_ih[256 + j];
        float4 bhn4 = *(const float4*)&b_hh[256 + j];
        {
            float4 u = *(const float4*)&b_hh[j];
            br4.x += u.x; br4.y += u.y; br4.z += u.z; br4.w += u.w;
            u = *(const float4*)&b_hh[128 + j];
            bz4.x += u.x; bz4.y += u.y; bz4.z += u.z; bz4.w += u.w;
        }
        uint2 uh = *(const uint2*)&hH[(size_t)n_g * H + j];
        uint2 ul = *(const uint2*)&hL[(size_t)n_g * H + j];
        float ho[4];
        ho[0] = bf2f(uh.x & 0xffff) + bf2f(ul.x & 0xffff);
        ho[1] = bf2f(uh.x >> 16) + bf2f(ul.x >> 16);
        ho[2] = bf2f(uh.y & 0xffff) + bf2f(ul.y & 0xffff);
        ho[3] = bf2f(uh.y >> 16) + bf2f(ul.y >> 16);
        unsigned long long packH = 0, packL = 0;
#define EPI(C, IDX)                                                                  \
        {                                                                            \
            float r_ = sigmoidf_(rv.C + br4.C);                                      \
            float z_ = sigmoidf_(zv.C + bz4.C);                                      \
            float ng = tanhf(iv.C + bin4.C + r_ * (nv.C + bhn4.C));                  \
            float hn = (1.f - z_) * ng + z_ * ho[IDX];                               \
            unsigned short hb = f2bf(hn);                                            \
            unsigned short lb = f2bf(hn - bf2f(hb));                                 \
            packH |= ((unsigned long long)hb) << (16 * IDX);                         \
            packL |= ((unsigned long long)lb) << (16 * IDX);                         \
        }
        EPI(x, 0) EPI(y, 1) EPI(z, 2) EPI(w, 3)
#undef EPI
        *(unsigned long long*)&hH[(size_t)n_g * H + j] = packH;
        *(unsigned long long*)&hL[(size_t)n_g * H + j] = packL;
    }
}

// ---------------- final linear + relu + LDS-staged per-graph accumulation ----------------
__global__ __launch_bounds__(256) void k_out(const unsigned short* __restrict__ hH,
                                             const unsigned short* __restrict__ hL,
                                             const float* __restrict__ lw,
                                             const float* __restrict__ lb,
                                             const int* __restrict__ batch,
                                             float* __restrict__ unc,
                                             float* __restrict__ gsum,
                                             float* __restrict__ gcnt) {
    __shared__ float sgs[G_GRAPHS];
    __shared__ float sgc[G_GRAPHS];
    const int t = threadIdx.x;
    if (t < G_GRAPHS) { sgs[t] = 0.f; sgc[t] = 0.f; }
    __syncthreads();
    const int lane = t & 63;
    const int grp = t >> 6;
    const float2 wv = *(const float2*)&lw[lane * 2];
    const float lbv = lb[0];
    const int base = blockIdx.x * 64;
#pragma unroll 4
    for (int it = 0; it < 16; ++it) {
        int n = base + it * 4 + grp;
        if (n < N_NODES) {
            unsigned int uh = *(const unsigned int*)&hH[(size_t)n * H + lane * 2];
            unsigned int ul = *(const unsigned int*)&hL[(size_t)n * H + lane * 2];
            float h0 = bf2f(uh & 0xffff) + bf2f(ul & 0xffff);
            float h1 = bf2f(uh >> 16) + bf2f(ul >> 16);
            float v = fmaxf(h0, 0.f) * wv.x + fmaxf(h1, 0.f) * wv.y;
#pragma unroll
            for (int off = 32; off >= 1; off >>= 1) v += __shfl_xor(v, off, 64);
            if (lane == 0) {
                float o = v + lbv;
                unc[n] = o;
                int b = batch[n];
                atomicAdd(&sgs[b], o);
                atomicAdd(&sgc[b], 1.0f);
            }
        }
    }
    __syncthreads();
    if (t < G_GRAPHS && sgc[t] != 0.f) {
        atomicAdd(&gsum[t], sgs[t]);
        atomicAdd(&gcnt[t], sgc[t]);
    }
}

__global__ __launch_bounds__(256) void k_corr(const float* __restrict__ unc,
                                              const int* __restrict__ batch,
                                              const float* __restrict__ gsum,
                                              const float* __restrict__ gcnt,
                                              float* __restrict__ corr) {
    int n = blockIdx.x * 256 + threadIdx.x;
    if (n >= N_NODES) return;
    int b = batch[n];
    float mean = gsum[b] / fmaxf(gcnt[b], 1.0f);
    corr[n] = unc[n] - mean;
}

extern "C" void kernel_launch(void* const* d_in, const int* in_sizes, int n_in,
                              void* d_out, int out_size, void* d_ws, size_t ws_size,
                              hipStream_t stream) {
    const float* x      = (const float*)d_in[0];
    const int*   ei     = (const int*)d_in[1];
    const int*   batch  = (const int*)d_in[2];
    const float* W0     = (const float*)d_in[4];
    const float* conv_w = (const float*)d_in[5];
    const float* w_ih   = (const float*)d_in[6];
    const float* b_ih   = (const float*)d_in[7];
    const float* w_hh   = (const float*)d_in[8];
    const float* b_hh   = (const float*)d_in[9];
    const float* lin1_w = (const float*)d_in[10];
    const float* lin1_b = (const float*)d_in[11];

    float* out = (float*)d_out;
    float* ws  = (float*)d_ws;

    float* m    = ws;                       // NH floats
    float* gsum = ws + (size_t)NH;          // G
    float* gcnt = gsum + G_GRAPHS;          // G
    int*   deg    = (int*)(ws + NH + 128);
    int*   offs   = deg + N_NODES;          // N+1
    int*   cursor = offs + N_NODES + 1;
    int*   bsum   = cursor + N_NODES;
    int*   boff   = bsum + NBLK;
    int*   csr    = boff + NBLK;            // E
    // 16B-aligned ushort region
    unsigned short* aggH = (unsigned short*)(ws + NH + 128 + 1900200);
    unsigned short* aggL = aggH + (size_t)NH;
    unsigned short* hH   = aggL + (size_t)NH;
    unsigned short* hL   = hH + (size_t)NH;
    unsigned short* WfH  = hL + (size_t)NH;   // 131072
    unsigned short* WfL  = WfH + 131072;
    unsigned short* WcH  = WfL + 131072;      // 4 layers x 16384
    unsigned short* WcL  = WcH + 65536;
    float*          W0T  = (float*)(WcL + 65536);  // 4096 floats (16B aligned)

    float* out_corr  = out;                         // [N]
    float* out_embed = out + N_NODES;               // [N*H]
    float* out_unc   = out + N_NODES + (size_t)NH;  // [N]

    hipMemsetAsync(gsum, 0, 2 * G_GRAPHS * sizeof(float), stream);
    hipMemsetAsync(deg, 0, N_NODES * sizeof(int), stream);

    k_prepw<<<64, 256, 0, stream>>>(w_ih, w_hh, WfH, WfL);
    k_prepcw<<<32, 256, 0, stream>>>(conv_w, WcH, WcL);
    k_prepw0<<<16, 256, 0, stream>>>(W0, W0T);
    k_embed<<<(N_NODES + 63) / 64, 256, 0, stream>>>(x, W0T, hH, hL, out_embed);

    k_hist<<<(N_EDGES + 255) / 256, 256, 0, stream>>>(ei, deg);
    k_blocksum<<<NBLK, 256, 0, stream>>>(deg, bsum);
    k_topscan<<<1, 64, 0, stream>>>(bsum, boff);
    k_scanwrite<<<NBLK, 256, 0, stream>>>(deg, boff, offs, cursor);
    k_scatter<<<(N_EDGES + 255) / 256, 256, 0, stream>>>(ei, cursor, csr);

    for (int l = 0; l < L_LAYERS; ++l) {
        k_conv<<<N_NODES / 32, 256, 0, stream>>>(hH, hL, WcH + (size_t)l * 16384,
                                                 WcL + (size_t)l * 16384, m);
        k_agg<<<N_NODES / 4, 256, 0, stream>>>(offs, csr, m, aggH, aggL);
        k_ggru<<<N_NODES / 32, 256, 0, stream>>>(aggH, aggL, hH, hL, WfH, WfL, b_ih, b_hh);
    }

    k_out<<<(N_NODES + 63) / 64, 256, 0, stream>>>(hH, hL, lin1_w, lin1_b, batch, out_unc, gsum, gcnt);
    k_corr<<<(N_NODES + 255) / 256, 256, 0, stream>>>(out_unc, batch, gsum, gcnt, out_corr);
}

// Round 7
// 1398.937 us; speedup vs baseline: 11.1398x; 1.0114x over previous
//
#include <hip/hip_runtime.h>

#define N_NODES 100000
#define N_EDGES 1600000
#define F_IN 32
#define H 128
#define H3 384
#define L_LAYERS 4
#define G_GRAPHS 64
#define NH (N_NODES * H)
#define SCAN_BS 1024
#define NBLK ((N_NODES + SCAN_BS - 1) / SCAN_BS)

typedef short bfrag __attribute__((ext_vector_type(8)));   // 8 bf16 = 4 VGPR
typedef float facc __attribute__((ext_vector_type(4)));    // 4 fp32 acc
typedef unsigned short u16x8 __attribute__((ext_vector_type(8)));

__device__ __forceinline__ float sigmoidf_(float x) { return 1.0f / (1.0f + __expf(-x)); }
__device__ __forceinline__ float bf2f(unsigned int u) { return __uint_as_float(u << 16); }
__device__ __forceinline__ unsigned short f2bf(float f) {
    unsigned int b = __float_as_uint(f);
    return (unsigned short)((b + 0x7FFF + ((b >> 16) & 1)) >> 16);
}
__device__ __forceinline__ facc mfma16(bfrag a, bfrag b, facc c) {
    return __builtin_amdgcn_mfma_f32_16x16x32_bf16(a, b, c, 0, 0, 0);
}

// ---------------- prep: W0T[32][128] = W0[j][k] transposed (once per call) ----------------
__global__ __launch_bounds__(256) void k_prepw0(const float* __restrict__ W0,
                                                float* __restrict__ W0T) {
    int tid = blockIdx.x * 256 + threadIdx.x;  // [0, 4096)
    int k = tid >> 7, j = tid & 127;
    W0T[tid] = W0[j * F_IN + k];
}

// ---------------- embed: 64 nodes/block, LDS-tiled, vectorized writes ----------------
__global__ __launch_bounds__(256) void k_embed(const float* __restrict__ x,
                                               const float* __restrict__ W0T,
                                               unsigned short* __restrict__ hH,
                                               unsigned short* __restrict__ hL,
                                               float* __restrict__ out_embed) {
    __shared__ float w0s[32][128];  // 16 KB, W0T staged
    __shared__ float xsT[32][64];   // 8 KB, x tile transposed: xsT[k][n_l]
    const int t = threadIdx.x;
    const int nb = blockIdx.x * 64;
    {
        float4* d = (float4*)&w0s[0][0];
        const float4* s = (const float4*)W0T;
#pragma unroll
        for (int i = 0; i < 4; ++i) d[t + 256 * i] = s[t + 256 * i];
    }
    {
        int n_l = t >> 2, k0 = (t & 3) * 8;
        int n = nb + n_l;
        float4 a = make_float4(0.f, 0.f, 0.f, 0.f), b = a;
        if (n < N_NODES) {
            a = *(const float4*)&x[(size_t)n * F_IN + k0];
            b = *(const float4*)&x[(size_t)n * F_IN + k0 + 4];
        }
        xsT[k0 + 0][n_l] = a.x; xsT[k0 + 1][n_l] = a.y;
        xsT[k0 + 2][n_l] = a.z; xsT[k0 + 3][n_l] = a.w;
        xsT[k0 + 4][n_l] = b.x; xsT[k0 + 5][n_l] = b.y;
        xsT[k0 + 6][n_l] = b.z; xsT[k0 + 7][n_l] = b.w;
    }
    __syncthreads();
    const int n0 = (t >> 5) * 8;   // 8 nodes per thread
    const int j0 = (t & 31) * 4;   // 4 cols per thread
    float4 acc[8];
#pragma unroll
    for (int i = 0; i < 8; ++i) acc[i] = make_float4(0.f, 0.f, 0.f, 0.f);
#pragma unroll 8
    for (int k = 0; k < 32; ++k) {
        float4 w = *(const float4*)&w0s[k][j0];
        float4 va = *(const float4*)&xsT[k][n0];
        float4 vb = *(const float4*)&xsT[k][n0 + 4];
        float xv[8] = {va.x, va.y, va.z, va.w, vb.x, vb.y, vb.z, vb.w};
#pragma unroll
        for (int i = 0; i < 8; ++i) {
            acc[i].x = fmaf(xv[i], w.x, acc[i].x);
            acc[i].y = fmaf(xv[i], w.y, acc[i].y);
            acc[i].z = fmaf(xv[i], w.z, acc[i].z);
            acc[i].w = fmaf(xv[i], w.w, acc[i].w);
        }
    }
#pragma unroll
    for (int i = 0; i < 8; ++i) {
        int n = nb + n0 + i;
        if (n < N_NODES) {
            float4 v;
            v.x = sigmoidf_(acc[i].x); v.y = sigmoidf_(acc[i].y);
            v.z = sigmoidf_(acc[i].z); v.w = sigmoidf_(acc[i].w);
            *(float4*)&out_embed[(size_t)n * H + j0] = v;
            unsigned short h0 = f2bf(v.x), h1 = f2bf(v.y), h2 = f2bf(v.z), h3 = f2bf(v.w);
            unsigned short l0 = f2bf(v.x - bf2f(h0)), l1 = f2bf(v.y - bf2f(h1));
            unsigned short l2 = f2bf(v.z - bf2f(h2)), l3 = f2bf(v.w - bf2f(h3));
            uint2 ph, pl;
            ph.x = (unsigned int)h0 | ((unsigned int)h1 << 16);
            ph.y = (unsigned int)h2 | ((unsigned int)h3 << 16);
            pl.x = (unsigned int)l0 | ((unsigned int)l1 << 16);
            pl.y = (unsigned int)l2 | ((unsigned int)l3 << 16);
            *(uint2*)&hH[(size_t)n * H + j0] = ph;
            *(uint2*)&hL[(size_t)n * H + j0] = pl;
        }
    }
}

// ---------------- CSR build ----------------
__global__ __launch_bounds__(256) void k_hist(const int* __restrict__ ei, int* __restrict__ deg) {
    int e = blockIdx.x * 256 + threadIdx.x;
    if (e >= N_EDGES) return;
    atomicAdd(&deg[ei[N_EDGES + e]], 1);
}

__global__ __launch_bounds__(256) void k_blocksum(const int* __restrict__ deg, int* __restrict__ bsum) {
    int b = blockIdx.x, t = threadIdx.x;
    int base = b * SCAN_BS + t * 4;
    int s = 0;
#pragma unroll
    for (int i = 0; i < 4; ++i) {
        int idx = base + i;
        if (idx < N_NODES) s += deg[idx];
    }
#pragma unroll
    for (int off = 1; off < 64; off <<= 1) s += __shfl_xor(s, off, 64);
    __shared__ int wtot[4];
    if ((t & 63) == 0) wtot[t >> 6] = s;
    __syncthreads();
    if (t == 0) bsum[b] = wtot[0] + wtot[1] + wtot[2] + wtot[3];
}

__global__ void k_topscan(const int* __restrict__ bsum, int* __restrict__ boff) {
    if (threadIdx.x == 0 && blockIdx.x == 0) {
        int acc = 0;
        for (int i = 0; i < NBLK; ++i) { boff[i] = acc; acc += bsum[i]; }
    }
}

__global__ __launch_bounds__(256) void k_scanwrite(const int* __restrict__ deg,
                                                   const int* __restrict__ boff,
                                                   int* __restrict__ offs,
                                                   int* __restrict__ cursor) {
    int b = blockIdx.x, t = threadIdx.x;
    int base = b * SCAN_BS + t * 4;
    int v[4];
    int s = 0;
#pragma unroll
    for (int i = 0; i < 4; ++i) {
        int idx = base + i;
        v[i] = (idx < N_NODES) ? deg[idx] : 0;
        s += v[i];
    }
    int lane = t & 63, w = t >> 6;
    int inc = s;
#pragma unroll
    for (int off = 1; off < 64; off <<= 1) {
        int u = __shfl_up(inc, off, 64);
        if (lane >= off) inc += u;
    }
    __shared__ int wtot[4];
    if (lane == 63) wtot[w] = inc;
    __syncthreads();
    int wpre = 0;
#pragma unroll
    for (int i = 0; i < 4; ++i)
        if (i < w) wpre += wtot[i];
    int run = inc - s + wpre + boff[b];
#pragma unroll
    for (int i = 0; i < 4; ++i) {
        int idx = base + i;
        if (idx < N_NODES) { offs[idx] = run; cursor[idx] = run; run += v[i]; }
    }
    if (b == 0 && t == 0) offs[N_NODES] = N_EDGES;
}

__global__ __launch_bounds__(256) void k_scatter(const int* __restrict__ ei,
                                                 int* __restrict__ cursor,
                                                 int* __restrict__ csr) {
    int e = blockIdx.x * 256 + threadIdx.x;
    if (e >= N_EDGES) return;
    int d = ei[N_EDGES + e];
    int pos = atomicAdd(&cursor[d], 1);
    csr[pos] = ei[e];
}

// ---------------- prep: GRU gate weights W2[256][512] fragment-major split bf16 ----------
__global__ __launch_bounds__(256) void k_prepw(const float* __restrict__ w_ih,
                                               const float* __restrict__ w_hh,
                                               unsigned short* __restrict__ WfH,
                                               unsigned short* __restrict__ WfL) {
    int tid = blockIdx.x * 256 + threadIdx.x;  // [0, 16384)
    int kc = tid >> 11;
    int ntg = (tid >> 6) & 31;
    int l = tid & 63;
    int c = ntg * 16 + (l & 15);
    int g = c >> 7;
    int jg = c & 127;
#pragma unroll
    for (int j = 0; j < 8; ++j) {
        int k = kc * 32 + ((l >> 4) << 3) + j;
        float val;
        if (k < 128) {
            val = (g < 3) ? w_ih[(g * 128 + jg) * 128 + k] : 0.f;
        } else {
            int k2 = k - 128;
            if (g == 2) val = 0.f;
            else val = w_hh[((g == 3 ? 256 : g * 128) + jg) * 128 + k2];
        }
        unsigned short hi = f2bf(val);
        WfH[tid * 8 + j] = hi;
        WfL[tid * 8 + j] = f2bf(val - bf2f(hi));
    }
}

// ---------------- prep: conv weights [L][128][128] fragment-major split bf16 ----------
__global__ __launch_bounds__(256) void k_prepcw(const float* __restrict__ conv_w,
                                                unsigned short* __restrict__ WcH,
                                                unsigned short* __restrict__ WcL) {
    int tid = blockIdx.x * 256 + threadIdx.x;  // [0, 8192)
    int lyr = tid >> 11;
    int rem = tid & 2047;
    int kc = rem >> 9;
    int ntg = (rem >> 6) & 7;
    int l = rem & 63;
    int c = ntg * 16 + (l & 15);
#pragma unroll
    for (int j = 0; j < 8; ++j) {
        int k = kc * 32 + ((l >> 4) << 3) + j;
        float val = conv_w[(size_t)lyr * H * H + k * H + c];
        unsigned short hi = f2bf(val);
        WcH[tid * 8 + j] = hi;
        WcL[tid * 8 + j] = f2bf(val - bf2f(hi));
    }
}

// ---------------- conv (MFMA): m = h @ conv_w[l], split-bf16 3-term ----------------
__global__ __launch_bounds__(256) void k_conv(const unsigned short* __restrict__ hH,
                                              const unsigned short* __restrict__ hL,
                                              const unsigned short* __restrict__ WcH,
                                              const unsigned short* __restrict__ WcL,
                                              float* __restrict__ m) {
    __shared__ short Ast[2][2][64][8];   // [hi/lo][mtile][lane][8] = 4 KB
    const int t = threadIdx.x;
    const int wv = t >> 6, l = t & 63;
    const int nb = blockIdx.x * 32;

    facc acc[2][2];
#pragma unroll
    for (int mt = 0; mt < 2; ++mt)
#pragma unroll
        for (int nt = 0; nt < 2; ++nt) acc[mt][nt] = (facc)(0.f);

    const int part = wv >> 1, mt_s = wv & 1;
    const int srow = nb + mt_s * 16 + (l & 15);
    const int kb8 = (l >> 4) << 3;
    const unsigned short* hP = part ? hL : hH;

    bfrag sA = *(const bfrag*)(hP + (size_t)srow * H + kb8);  // kc=0
    for (int kc = 0; kc < 4; ++kc) {
        __syncthreads();
        *(bfrag*)&Ast[part][mt_s][l][0] = sA;
        if (kc < 3) sA = *(const bfrag*)(hP + (size_t)srow * H + (kc + 1) * 32 + kb8);
        __syncthreads();
        bfrag a0h = *(const bfrag*)&Ast[0][0][l][0];
        bfrag a1h = *(const bfrag*)&Ast[0][1][l][0];
        bfrag a0l = *(const bfrag*)&Ast[1][0][l][0];
        bfrag a1l = *(const bfrag*)&Ast[1][1][l][0];
#pragma unroll
        for (int nt = 0; nt < 2; ++nt) {
            int ntg = wv * 2 + nt;
            const short* bh = (const short*)WcH + (size_t)((kc * 8 + ntg) * 64 + l) * 8;
            const short* bl = (const short*)WcL + (size_t)((kc * 8 + ntg) * 64 + l) * 8;
            bfrag wH = *(const bfrag*)bh;
            bfrag wL = *(const bfrag*)bl;
            acc[0][nt] = mfma16(a0h, wH, acc[0][nt]);
            acc[0][nt] = mfma16(a0h, wL, acc[0][nt]);
            acc[0][nt] = mfma16(a0l, wH, acc[0][nt]);
            acc[1][nt] = mfma16(a1h, wH, acc[1][nt]);
            acc[1][nt] = mfma16(a1h, wL, acc[1][nt]);
            acc[1][nt] = mfma16(a1l, wH, acc[1][nt]);
        }
    }
#pragma unroll
    for (int mt = 0; mt < 2; ++mt)
#pragma unroll
        for (int nt = 0; nt < 2; ++nt) {
            int r0 = mt * 16 + ((l >> 4) << 2);
            int c = wv * 32 + nt * 16 + (l & 15);
#pragma unroll
            for (int reg = 0; reg < 4; ++reg)
                m[(size_t)(nb + r0 + reg) * H + c] = acc[mt][nt][reg];
        }
}

// ---------------- aggregate: agg[n] = sum_{in-edges} m[src]; emit split bf16 ----------
__global__ __launch_bounds__(256) void k_agg(const int* __restrict__ offs,
                                             const int* __restrict__ csr,
                                             const float* __restrict__ m,
                                             unsigned short* __restrict__ aggH,
                                             unsigned short* __restrict__ aggL) {
    int t = threadIdx.x;
    int n = blockIdx.x * 4 + (t >> 6);
    int lane = t & 63;
    int beg = offs[n], end = offs[n + 1];
    float2 acc = make_float2(0.f, 0.f);
    int i = beg;
    for (; i + 1 < end; i += 2) {
        int s0 = csr[i], s1 = csr[i + 1];
        float2 a = *(const float2*)&m[(size_t)s0 * H + lane * 2];
        float2 b = *(const float2*)&m[(size_t)s1 * H + lane * 2];
        acc.x += a.x + b.x;
        acc.y += a.y + b.y;
    }
    if (i < end) {
        float2 a = *(const float2*)&m[(size_t)csr[i] * H + lane * 2];
        acc.x += a.x;
        acc.y += a.y;
    }
    unsigned short hx = f2bf(acc.x);
    unsigned short lx = f2bf(acc.x - bf2f(hx));
    unsigned short hy = f2bf(acc.y);
    unsigned short ly = f2bf(acc.y - bf2f(hy));
    *(unsigned int*)&aggH[(size_t)n * H + lane * 2] = (unsigned int)hx | ((unsigned int)hy << 16);
    *(unsigned int*)&aggL[(size_t)n * H + lane * 2] = (unsigned int)lx | ((unsigned int)ly << 16);
}

// ---------------- fused MFMA gates GEMM + in-register GRU epilogue ----------------
// block: 32 rows x 512 cols; 4 waves. Wave wv owns col-slice wv*32..wv*32+31 of ALL 4 gates
// (col = gate*128 + wv*32 + nt*16 + (lane&15)), so r/z/i/n stay in-register per lane.
// No gates LDS -> LDS = 4 KB -> occupancy wave-slot-limited instead of LDS-limited.
__global__ __launch_bounds__(256, 4) void k_ggru(const unsigned short* __restrict__ aggH,
                                                 const unsigned short* __restrict__ aggL,
                                                 unsigned short* __restrict__ hH,
                                                 unsigned short* __restrict__ hL,
                                                 const unsigned short* __restrict__ WfH,
                                                 const unsigned short* __restrict__ WfL,
                                                 const float* __restrict__ b_ih,
                                                 const float* __restrict__ b_hh) {
    __shared__ short Ast[2][2][64][8];   // [hi/lo][mtile][lane][8] = 4 KB
    const int t = threadIdx.x;
    const int wv = t >> 6, l = t & 63;
    const int nb = blockIdx.x * 32;

    facc acc[4][2][2];  // [gate][mtile][nt] = 16 facc = 64 VGPR
#pragma unroll
    for (int g = 0; g < 4; ++g)
#pragma unroll
        for (int mt = 0; mt < 2; ++mt)
#pragma unroll
            for (int nt = 0; nt < 2; ++nt) acc[g][mt][nt] = (facc)(0.f);

    // per-thread bias values (col j = wv*32 + nt*16 + (l&15) within each gate)
    const int jb = wv * 32 + (l & 15);
    float brs[2], bzs[2], bis[2], bns[2];
#pragma unroll
    for (int nt = 0; nt < 2; ++nt) {
        int c = jb + nt * 16;
        brs[nt] = b_ih[c] + b_hh[c];
        bzs[nt] = b_ih[128 + c] + b_hh[128 + c];
        bis[nt] = b_ih[256 + c];
        bns[nt] = b_hh[256 + c];
    }

    // staging role: wave wv stages (part = wv>>1 [hi/lo], mt_s = wv&1)
    const int part = wv >> 1, mt_s = wv & 1;
    const int srow = nb + mt_s * 16 + (l & 15);
    const int kb8 = (l >> 4) << 3;
    const unsigned short* aggP = part ? aggL : aggH;
    const unsigned short* hP = part ? hL : hH;

    bfrag sA = *(const bfrag*)(aggP + (size_t)srow * H + kb8);  // kc=0
    for (int kc = 0; kc < 8; ++kc) {
        __syncthreads();
        *(bfrag*)&Ast[part][mt_s][l][0] = sA;
        if (kc < 7) {
            int kn = kc + 1;
            const unsigned short* base = (kn < 4) ? aggP : hP;
            sA = *(const bfrag*)(base + (size_t)srow * H + ((kn & 3) << 5) + kb8);
        }
        __syncthreads();
        bfrag a0h = *(const bfrag*)&Ast[0][0][l][0];
        bfrag a1h = *(const bfrag*)&Ast[0][1][l][0];
        bfrag a0l = *(const bfrag*)&Ast[1][0][l][0];
        bfrag a1l = *(const bfrag*)&Ast[1][1][l][0];
        // B frags: ntg = gate*8 + wv*2 + nt  (shorts: gate -> +4096, nt -> +512)
        const short* bh = (const short*)WfH + (size_t)(((kc * 32 + wv * 2) * 64) + l) * 8;
        const short* bl = (const short*)WfL + (size_t)(((kc * 32 + wv * 2) * 64) + l) * 8;
#pragma unroll
        for (int g = 0; g < 4; ++g)
#pragma unroll
            for (int nt = 0; nt < 2; ++nt) {
                bfrag wH = *(const bfrag*)(bh + g * 4096 + nt * 512);
                bfrag wL = *(const bfrag*)(bl + g * 4096 + nt * 512);
                acc[g][0][nt] = mfma16(a0h, wH, acc[g][0][nt]);
                acc[g][0][nt] = mfma16(a0h, wL, acc[g][0][nt]);
                acc[g][0][nt] = mfma16(a0l, wH, acc[g][0][nt]);
                acc[g][1][nt] = mfma16(a1h, wH, acc[g][1][nt]);
                acc[g][1][nt] = mfma16(a1h, wL, acc[g][1][nt]);
                acc[g][1][nt] = mfma16(a1l, wH, acc[g][1][nt]);
            }
    }

    // in-register GRU epilogue. C/D layout: col=lane&15 (-> our col slice), row=(lane>>4)*4+reg
#pragma unroll
    for (int mt = 0; mt < 2; ++mt)
#pragma unroll
        for (int nt = 0; nt < 2; ++nt) {
            int j = jb + nt * 16;                       // col within gate (0..127)
            int r0 = nb + mt * 16 + ((l >> 4) << 2);    // global row base
#pragma unroll
            for (int reg = 0; reg < 4; ++reg) {
                size_t idx = (size_t)(r0 + reg) * H + j;
                float r_ = sigmoidf_(acc[0][mt][nt][reg] + brs[nt]);
                float z_ = sigmoidf_(acc[1][mt][nt][reg] + bzs[nt]);
                float ng = tanhf(acc[2][mt][nt][reg] + bis[nt] + r_ * (acc[3][mt][nt][reg] + bns[nt]));
                float ho = bf2f(hH[idx]) + bf2f(hL[idx]);
                float hn = (1.f - z_) * ng + z_ * ho;
                unsigned short hb = f2bf(hn);
                hH[idx] = hb;
                hL[idx] = f2bf(hn - bf2f(hb));
            }
        }
}

// ---------------- final linear + relu + LDS-staged per-graph accumulation ----------------
__global__ __launch_bounds__(256) void k_out(const unsigned short* __restrict__ hH,
                                             const unsigned short* __restrict__ hL,
                                             const float* __restrict__ lw,
                                             const float* __restrict__ lb,
                                             const int* __restrict__ batch,
                                             float* __restrict__ unc,
                                             float* __restrict__ gsum,
                                             float* __restrict__ gcnt) {
    __shared__ float sgs[G_GRAPHS];
    __shared__ float sgc[G_GRAPHS];
    const int t = threadIdx.x;
    if (t < G_GRAPHS) { sgs[t] = 0.f; sgc[t] = 0.f; }
    __syncthreads();
    const int lane = t & 63;
    const int grp = t >> 6;
    const float2 wv = *(const float2*)&lw[lane * 2];
    const float lbv = lb[0];
    const int base = blockIdx.x * 64;
#pragma unroll 4
    for (int it = 0; it < 16; ++it) {
        int n = base + it * 4 + grp;
        if (n < N_NODES) {
            unsigned int uh = *(const unsigned int*)&hH[(size_t)n * H + lane * 2];
            unsigned int ul = *(const unsigned int*)&hL[(size_t)n * H + lane * 2];
            float h0 = bf2f(uh & 0xffff) + bf2f(ul & 0xffff);
            float h1 = bf2f(uh >> 16) + bf2f(ul >> 16);
            float v = fmaxf(h0, 0.f) * wv.x + fmaxf(h1, 0.f) * wv.y;
#pragma unroll
            for (int off = 32; off >= 1; off >>= 1) v += __shfl_xor(v, off, 64);
            if (lane == 0) {
                float o = v + lbv;
                unc[n] = o;
                int b = batch[n];
                atomicAdd(&sgs[b], o);
                atomicAdd(&sgc[b], 1.0f);
            }
        }
    }
    __syncthreads();
    if (t < G_GRAPHS && sgc[t] != 0.f) {
        atomicAdd(&gsum[t], sgs[t]);
        atomicAdd(&gcnt[t], sgc[t]);
    }
}

__global__ __launch_bounds__(256) void k_corr(const float* __restrict__ unc,
                                              const int* __restrict__ batch,
                                              const float* __restrict__ gsum,
                                              const float* __restrict__ gcnt,
                                              float* __restrict__ corr) {
    int n = blockIdx.x * 256 + threadIdx.x;
    if (n >= N_NODES) return;
    int b = batch[n];
    float mean = gsum[b] / fmaxf(gcnt[b], 1.0f);
    corr[n] = unc[n] - mean;
}

extern "C" void kernel_launch(void* const* d_in, const int* in_sizes, int n_in,
                              void* d_out, int out_size, void* d_ws, size_t ws_size,
                              hipStream_t stream) {
    const float* x      = (const float*)d_in[0];
    const int*   ei     = (const int*)d_in[1];
    const int*   batch  = (const int*)d_in[2];
    const float* W0     = (const float*)d_in[4];
    const float* conv_w = (const float*)d_in[5];
    const float* w_ih   = (const float*)d_in[6];
    const float* b_ih   = (const float*)d_in[7];
    const float* w_hh   = (const float*)d_in[8];
    const float* b_hh   = (const float*)d_in[9];
    const float* lin1_w = (const float*)d_in[10];
    const float* lin1_b = (const float*)d_in[11];

    float* out = (float*)d_out;
    float* ws  = (float*)d_ws;

    float* m    = ws;                       // NH floats
    float* gsum = ws + (size_t)NH;          // G
    float* gcnt = gsum + G_GRAPHS;          // G
    int*   deg    = (int*)(ws + NH + 128);
    int*   offs   = deg + N_NODES;          // N+1
    int*   cursor = offs + N_NODES + 1;
    int*   bsum   = cursor + N_NODES;
    int*   boff   = bsum + NBLK;
    int*   csr    = boff + NBLK;            // E
    // 16B-aligned ushort region
    unsigned short* aggH = (unsigned short*)(ws + NH + 128 + 1900200);
    unsigned short* aggL = aggH + (size_t)NH;
    unsigned short* hH   = aggL + (size_t)NH;
    unsigned short* hL   = hH + (size_t)NH;
    unsigned short* WfH  = hL + (size_t)NH;   // 131072
    unsigned short* WfL  = WfH + 131072;
    unsigned short* WcH  = WfL + 131072;      // 4 layers x 16384
    unsigned short* WcL  = WcH + 65536;
    float*          W0T  = (float*)(WcL + 65536);  // 4096 floats (16B aligned)

    float* out_corr  = out;                         // [N]
    float* out_embed = out + N_NODES;               // [N*H]
    float* out_unc   = out + N_NODES + (size_t)NH;  // [N]

    hipMemsetAsync(gsum, 0, 2 * G_GRAPHS * sizeof(float), stream);
    hipMemsetAsync(deg, 0, N_NODES * sizeof(int), stream);

    k_prepw<<<64, 256, 0, stream>>>(w_ih, w_hh, WfH, WfL);
    k_prepcw<<<32, 256, 0, stream>>>(conv_w, WcH, WcL);
    k_prepw0<<<16, 256, 0, stream>>>(W0, W0T);
    k_embed<<<(N_NODES + 63) / 64, 256, 0, stream>>>(x, W0T, hH, hL, out_embed);

    k_hist<<<(N_EDGES + 255) / 256, 256, 0, stream>>>(ei, deg);
    k_blocksum<<<NBLK, 256, 0, stream>>>(deg, bsum);
    k_topscan<<<1, 64, 0, stream>>>(bsum, boff);
    k_scanwrite<<<NBLK, 256, 0, stream>>>(deg, boff, offs, cursor);
    k_scatter<<<(N_EDGES + 255) / 256, 256, 0, stream>>>(ei, cursor, csr);

    for (int l = 0; l < L_LAYERS; ++l) {
        k_conv<<<N_NODES / 32, 256, 0, stream>>>(hH, hL, WcH + (size_t)l * 16384,
                                                 WcL + (size_t)l * 16384, m);
        k_agg<<<N_NODES / 4, 256, 0, stream>>>(offs, csr, m, aggH, aggL);
        k_ggru<<<N_NODES / 32, 256, 0, stream>>>(aggH, aggL, hH, hL, WfH, WfL, b_ih, b_hh);
    }

    k_out<<<(N_NODES + 63) / 64, 256, 0, stream>>>(hH, hL, lin1_w, lin1_b, batch, out_unc, gsum, gcnt);
    k_corr<<<(N_NODES + 255) / 256, 256, 0, stream>>>(out_unc, batch, gsum, gcnt, out_corr);
}